// Round 2
// baseline (842.506 us; speedup 1.0000x reference)
//
#include <hip/hip_runtime.h>

typedef short s16x8 __attribute__((ext_vector_type(8)));
typedef float f32x4 __attribute__((ext_vector_type(4)));
using u16 = unsigned short;
using ll = long long;

// ---------- bf16 helpers (bit-level, RNE) ----------
__device__ inline u16 f2b(float f) {
    union { float f; unsigned int i; } u; u.f = f;
    unsigned int r = u.i + 0x7FFFu + ((u.i >> 16) & 1u);
    return (u16)(r >> 16);
}
__device__ inline float b2f(u16 v) {
    union { unsigned int i; float f; } u; u.i = ((unsigned int)v) << 16; return u.f;
}
__device__ inline s16x8 zero8() {
    s16x8 z; z[0]=0;z[1]=0;z[2]=0;z[3]=0;z[4]=0;z[5]=0;z[6]=0;z[7]=0; return z;
}

// ---------- problem constants ----------
#define BATCH 8
#define CIN   512
#define HW    3136   // 56*56
#define CM    128
#define CN    64
#define MPROJ 640    // 128+64+64+128+128+128
#define PADW  58
#define PADHW 3364   // 58*58
#define GUARD 64
#define UROWS (PADHW + 2*GUARD)  // 3492

// ws offsets (bytes)
#define OFF_XT     0LL                                 // [8][3136][512] bf16  25,690,112
#define OFF_P      25690112LL                          // [8][640][3136] bf16  32,112,640
#define OFF_SVT    57802752LL                          // [8][3136][64]  bf16   3,211,264
#define OFF_AST    61014016LL                          // [8][3136][128] bf16   6,422,528
#define OFF_G      67436544LL                          // [8][128][64]   bf16     131,072
#define OFF_H      67567616LL                          // [8][128][128]  bf16     262,144
#define OFF_ZT     67829760LL                          // [8][3136][128] bf16   6,422,528
#define OFF_ZST    74252288LL                          // [8][3136][128] bf16   6,422,528
#define OFF_UPAD   80674816LL                          // [8][3492][512] bf16  28,606,464
#define OFF_WCAT   109281280LL                         // [640][512] bf16         655,360
#define OFF_BCAT   109936640LL                         // [640] f32                 2,560
#define OFF_WEB    109939200LL                         // [512][128] bf16         131,072
#define OFF_WS9    110070272LL                         // [9][512][512] bf16    4,718,592
#define OFF_SCALE  114788864LL                         // [512] f32
#define OFF_SHIFT  114790912LL                         // [512] f32
#define WS_NEEDED  114792960LL

// ---------------------------------------------------------------------------
// prep: pack weights to bf16, fold bn
// ---------------------------------------------------------------------------
__global__ void prep_kernel(
    const float* __restrict__ WA,  const float* __restrict__ WB,  const float* __restrict__ WV,
    const float* __restrict__ WAs, const float* __restrict__ WBs, const float* __restrict__ WVs,
    const float* __restrict__ bA,  const float* __restrict__ bB,  const float* __restrict__ bV,
    const float* __restrict__ bAs, const float* __restrict__ bBs, const float* __restrict__ bVs,
    const float* __restrict__ WE,  const float* __restrict__ bng, const float* __restrict__ bnb,
    const float* __restrict__ bnm, const float* __restrict__ bnv, const float* __restrict__ Wout,
    u16* __restrict__ Wcat, float* __restrict__ bcat, u16* __restrict__ WEb,
    u16* __restrict__ Ws9, float* __restrict__ scale, float* __restrict__ shift)
{
    ll tid = (ll)blockIdx.x * blockDim.x + threadIdx.x;
    ll stride = (ll)gridDim.x * blockDim.x;
    // Wcat rows: A 0..127 | B 128..191 | V 192..255 | A_S 256..383 | B_S 384..511 | V_S 512..639
    for (ll i = tid; i < (ll)MPROJ * CIN; i += stride) {
        int o = (int)(i / CIN), c = (int)(i % CIN);
        float v;
        if      (o < 128) v = WA [(o      )*CIN + c];
        else if (o < 192) v = WB [(o - 128)*CIN + c];
        else if (o < 256) v = WV [(o - 192)*CIN + c];
        else if (o < 384) v = WAs[(o - 256)*CIN + c];
        else if (o < 512) v = WBs[(o - 384)*CIN + c];
        else              v = WVs[(o - 512)*CIN + c];
        Wcat[i] = f2b(v);
    }
    for (ll i = tid; i < MPROJ; i += stride) {
        int o = (int)i; float v;
        if      (o < 128) v = bA [o];
        else if (o < 192) v = bB [o - 128];
        else if (o < 256) v = bV [o - 192];
        else if (o < 384) v = bAs[o - 256];
        else if (o < 512) v = bBs[o - 384];
        else              v = bVs[o - 512];
        bcat[i] = v;
    }
    for (ll i = tid; i < (ll)CIN * CM; i += stride) WEb[i] = f2b(WE[i]);
    for (ll i = tid; i < 9LL * CIN * CIN; i += stride) {
        int s  = (int)(i / (CIN * CIN));
        int oc = (int)(i % (CIN * CIN));
        Ws9[i] = f2b(Wout[(ll)oc * 9 + s]);   // Wout[o][c][dy][dx] -> Ws9[s][o][c]
    }
    for (ll i = tid; i < CIN; i += stride) {
        float sc = bng[i] * rsqrtf(bnv[i] + 1e-5f);
        scale[i] = sc;
        shift[i] = bnb[i] - bnm[i] * sc;
    }
}

// ---------------------------------------------------------------------------
// transpose [R][C] -> [C][R], output bf16 (src fp32 or bf16). R,C mult of 32.
// ---------------------------------------------------------------------------
template<typename T>
__global__ __launch_bounds__(256) void transpose_kernel(
    const T* __restrict__ src, u16* __restrict__ dst,
    int R, int C, ll sS, ll sD)
{
    __shared__ u16 tile[32][33];
    int b  = blockIdx.z;
    int c0 = blockIdx.x << 5, r0 = blockIdx.y << 5;
    int tc = threadIdx.x & 31, tr = threadIdx.x >> 5;   // tr 0..7
    const T* s = src + sS * b;
    #pragma unroll
    for (int i = 0; i < 4; ++i) {
        int r = tr + i * 8;
        T v = s[(ll)(r0 + r) * C + c0 + tc];
        u16 u;
        if constexpr (sizeof(T) == 4) u = f2b((float)v);
        else                          u = (u16)v;
        tile[r][tc] = u;
    }
    __syncthreads();
    u16* d = dst + sD * b;
    #pragma unroll
    for (int i = 0; i < 4; ++i) {
        int c = tr + i * 8;
        d[(ll)(c0 + c) * R + r0 + tc] = tile[tc][c];
    }
}

// ---------------------------------------------------------------------------
// generic bf16 MFMA GEMM:  C[m,n] = sum_k A[m,k] * Bt[n,k]   (both row-major)
// BM=BN=128, BK=32, 256 thr = 4 waves (2x2), wave tile 64x64 = 4x4 frags.
// EPI: 0 = +rowBias -> bf16 C      (projection)
//      1 = plain -> bf16 C         (Zt / ZSt / G / H)
//      2 = +colBias, bn, relu -> write UpadT at remapped padded row
//      3 = same as 2 but += existing UpadT value += xT residual
// ---------------------------------------------------------------------------
template<int EPI>
__global__ __launch_bounds__(256) void gemm_bt_kernel(
    const u16* __restrict__ A, ll ldA, ll sA,
    const u16* __restrict__ Bt, ll ldB, ll sB,
    u16* __restrict__ C, ll ldC, ll sC,
    int M, int N, int K,
    const float* __restrict__ rowBias,
    const float* __restrict__ colBias,
    const float* __restrict__ scale,
    const float* __restrict__ shift,
    const u16* __restrict__ xT)
{
    __shared__ __align__(16) u16 As[128][40];
    __shared__ __align__(16) u16 Bs[128][40];
    const int b  = blockIdx.z;
    const int n0 = blockIdx.x * 128;
    const int m0 = blockIdx.y * 128;
    const int t  = threadIdx.x;
    const int lane = t & 63;
    const int wid  = t >> 6;
    const int wm   = (wid >> 1) * 64;
    const int wn   = (wid & 1) * 64;
    const int l15  = lane & 15;
    const int hi   = lane >> 4;

    f32x4 acc[4][4];
    #pragma unroll
    for (int i = 0; i < 4; ++i)
        #pragma unroll
        for (int j = 0; j < 4; ++j) { acc[i][j][0]=0.f; acc[i][j][1]=0.f; acc[i][j][2]=0.f; acc[i][j][3]=0.f; }

    const u16* Ab = A  + sA * b;
    const u16* Bb = Bt + sB * b;
    const int r0 = t >> 2;
    const int c0 = (t & 3) << 3;
    const int nk = K >> 5;

    for (int kc = 0; kc < nk; ++kc) {
        const int k0 = kc << 5;
        __syncthreads();
        #pragma unroll
        for (int h = 0; h < 2; ++h) {
            const int r = r0 + (h << 6);
            const int gm = m0 + r;
            s16x8 va = zero8();
            if (gm < M) va = *(const s16x8*)(Ab + (ll)gm * ldA + k0 + c0);
            *(s16x8*)&As[r][c0] = va;
            const int gn = n0 + r;
            s16x8 vb = zero8();
            if (gn < N) vb = *(const s16x8*)(Bb + (ll)gn * ldB + k0 + c0);
            *(s16x8*)&Bs[r][c0] = vb;
        }
        __syncthreads();
        s16x8 af[4], bfr[4];
        #pragma unroll
        for (int i = 0; i < 4; ++i) {
            af[i]  = *(const s16x8*)&As[wm + i*16 + l15][hi*8];
            bfr[i] = *(const s16x8*)&Bs[wn + i*16 + l15][hi*8];
        }
        #pragma unroll
        for (int i = 0; i < 4; ++i)
            #pragma unroll
            for (int j = 0; j < 4; ++j)
                acc[i][j] = __builtin_amdgcn_mfma_f32_16x16x32_bf16(af[i], bfr[j], acc[i][j], 0, 0, 0);
    }

    // epilogue. D frag layout: col = lane&15, row = (lane>>4)*4 + r  [measured m89/m91]
    #pragma unroll
    for (int i = 0; i < 4; ++i) {
        #pragma unroll
        for (int j = 0; j < 4; ++j) {
            const int n = n0 + wn + j*16 + l15;
            if (n >= N) continue;
            #pragma unroll
            for (int r = 0; r < 4; ++r) {
                const int m = m0 + wm + i*16 + hi*4 + r;
                if (m >= M) continue;
                float v = acc[i][j][r];
                if constexpr (EPI == 0) {
                    v += rowBias[m];
                    C[sC*b + (ll)m*ldC + n] = f2b(v);
                } else if constexpr (EPI == 1) {
                    C[sC*b + (ll)m*ldC + n] = f2b(v);
                } else {
                    v += colBias[n];
                    v = v * scale[n] + shift[n];
                    v = fmaxf(v, 0.f);
                    const int y = m / 56, xx = m % 56;       // m is the pixel index
                    const ll  u = GUARD + (ll)(y + 1) * PADW + (xx + 1);
                    u16* dst = C + sC*b + u*ldC + n;
                    if constexpr (EPI == 2) {
                        *dst = f2b(v);
                    } else {
                        float prev = b2f(*dst);
                        float xv   = b2f(xT[((ll)b*HW + m)*CIN + n]);
                        *dst = f2b(v + prev + xv);
                    }
                }
            }
        }
    }
}

// ---------------------------------------------------------------------------
// softmax over spatial (3136) for the 64 B-rows of P, in place (bf16)
// ---------------------------------------------------------------------------
__global__ __launch_bounds__(256) void softmax_rows_kernel(u16* __restrict__ P)
{
    __shared__ float red[4];
    __shared__ float red2[4];
    const int b = blockIdx.y, row = 128 + blockIdx.x;
    u16* p = P + ((ll)b * MPROJ + row) * HW;
    const int t = threadIdx.x;
    float vals[13];
    int cnt = 0;
    float m = -1e30f;
    for (int j = t; j < HW; j += 256) { float v = b2f(p[j]); vals[cnt++] = v; m = fmaxf(m, v); }
    #pragma unroll
    for (int o = 32; o; o >>= 1) m = fmaxf(m, __shfl_xor(m, o));
    const int wid = t >> 6;
    if ((t & 63) == 0) red[wid] = m;
    __syncthreads();
    m = fmaxf(fmaxf(red[0], red[1]), fmaxf(red[2], red[3]));
    float s = 0.f;
    for (int i = 0; i < cnt; ++i) { vals[i] = __expf(vals[i] - m); s += vals[i]; }
    #pragma unroll
    for (int o = 32; o; o >>= 1) s += __shfl_xor(s, o);
    if ((t & 63) == 0) red2[wid] = s;
    __syncthreads();
    s = red2[0] + red2[1] + red2[2] + red2[3];
    const float inv = 1.f / s;
    cnt = 0;
    for (int j = t; j < HW; j += 256) p[j] = f2b(vals[cnt++] * inv);
}

// ---------------------------------------------------------------------------
// channel softmax (over 64 or 128 rows) per pixel, in place.
// grid.y selects group: 0 = V(192,64) 1 = B_S(384,128) 2 = V_S(512,128)
// ---------------------------------------------------------------------------
__global__ void softmax_cols_kernel(u16* __restrict__ P)
{
    int idx = blockIdx.x * 256 + threadIdx.x;
    if (idx >= BATCH * HW) return;
    const int b = idx / HW, p = idx % HW;
    int off, n;
    if      (blockIdx.y == 0) { off = 192; n = 64;  }
    else if (blockIdx.y == 1) { off = 384; n = 128; }
    else                      { off = 512; n = 128; }
    u16* g = P + (ll)b * MPROJ * HW + (ll)off * HW + p;
    float m = -1e30f, s = 0.f;
    for (int i = 0; i < n; ++i) {
        float v  = b2f(g[(ll)i * HW]);
        float nm = fmaxf(m, v);
        s = s * __expf(m - nm) + __expf(v - nm);
        m = nm;
    }
    const float inv = 1.f / s;
    for (int i = 0; i < n; ++i) {
        const ll o = (ll)i * HW;
        g[o] = f2b(__expf(b2f(g[o]) - m) * inv);
    }
}

// ---------------------------------------------------------------------------
// conv3x3 as 9 shift-GEMMs over padded pixel domain.
// out[o, y, x] = bout[o] + sum_s sum_c Ws9[s][o][c] * UpadT[64 + (y+dy)*58 + (x+dx)][c]
// Grid: (27 n-tiles of 128 padded pixels, 4 m-tiles of 128 out-chans, 8 batch)
// ---------------------------------------------------------------------------
__global__ __launch_bounds__(256) void conv9_kernel(
    const u16* __restrict__ Ws9, const u16* __restrict__ UpadT,
    const float* __restrict__ bout, float* __restrict__ out)
{
    __shared__ __align__(16) u16 As[128][40];
    __shared__ __align__(16) u16 Bs[128][40];
    const int b  = blockIdx.z;
    const int n0 = blockIdx.x * 128;
    const int m0 = blockIdx.y * 128;
    const int t  = threadIdx.x;
    const int lane = t & 63;
    const int wid  = t >> 6;
    const int wm   = (wid >> 1) * 64;
    const int wn   = (wid & 1) * 64;
    const int l15  = lane & 15;
    const int hi   = lane >> 4;

    f32x4 acc[4][4];
    #pragma unroll
    for (int i = 0; i < 4; ++i)
        #pragma unroll
        for (int j = 0; j < 4; ++j) { acc[i][j][0]=0.f; acc[i][j][1]=0.f; acc[i][j][2]=0.f; acc[i][j][3]=0.f; }

    const u16* Ub = UpadT + (ll)b * UROWS * CIN;
    const int r0 = t >> 2;
    const int c0 = (t & 3) << 3;

    for (int s = 0; s < 9; ++s) {
        const int doff = (s / 3 - 1) * PADW + (s % 3 - 1);
        const u16* Ab = Ws9 + (ll)s * CIN * CIN;
        for (int kc = 0; kc < 16; ++kc) {
            const int k0 = kc << 5;
            __syncthreads();
            #pragma unroll
            for (int h = 0; h < 2; ++h) {
                const int r = r0 + (h << 6);
                *(s16x8*)&As[r][c0] = *(const s16x8*)(Ab + (ll)(m0 + r) * CIN + k0 + c0);
                int u = GUARD + n0 + doff + r;
                u = min(u, UROWS - 1);           // clamp: garbage feeds only discarded outputs
                *(s16x8*)&Bs[r][c0] = *(const s16x8*)(Ub + (ll)u * CIN + k0 + c0);
            }
            __syncthreads();
            s16x8 af[4], bfr[4];
            #pragma unroll
            for (int i = 0; i < 4; ++i) {
                af[i]  = *(const s16x8*)&As[wm + i*16 + l15][hi*8];
                bfr[i] = *(const s16x8*)&Bs[wn + i*16 + l15][hi*8];
            }
            #pragma unroll
            for (int i = 0; i < 4; ++i)
                #pragma unroll
                for (int j = 0; j < 4; ++j)
                    acc[i][j] = __builtin_amdgcn_mfma_f32_16x16x32_bf16(af[i], bfr[j], acc[i][j], 0, 0, 0);
        }
    }

    #pragma unroll
    for (int i = 0; i < 4; ++i) {
        #pragma unroll
        for (int j = 0; j < 4; ++j) {
            const int pc = n0 + wn + j*16 + l15;       // padded pixel index
            const int y = pc / PADW, xx = pc % PADW;
            if (y >= 1 && y <= 56 && xx >= 1 && xx <= 56) {
                const int p = (y - 1) * 56 + (xx - 1);
                #pragma unroll
                for (int r = 0; r < 4; ++r) {
                    const int m = m0 + wm + i*16 + hi*4 + r;
                    out[((ll)b * CIN + m) * HW + p] = acc[i][j][r] + bout[m];
                }
            }
        }
    }
}

// ---------------------------------------------------------------------------
extern "C" void kernel_launch(void* const* d_in, const int* in_sizes, int n_in,
                              void* d_out, int out_size, void* d_ws, size_t ws_size,
                              hipStream_t stream)
{
    const float* x    = (const float*)d_in[0];
    const float* WA   = (const float*)d_in[1];
    const float* bA   = (const float*)d_in[2];
    const float* WB   = (const float*)d_in[3];
    const float* bB   = (const float*)d_in[4];
    const float* WV   = (const float*)d_in[5];
    const float* bV   = (const float*)d_in[6];
    const float* WAs  = (const float*)d_in[7];
    const float* bAs  = (const float*)d_in[8];
    const float* WBs  = (const float*)d_in[9];
    const float* bBs  = (const float*)d_in[10];
    const float* WVs  = (const float*)d_in[11];
    const float* bVs  = (const float*)d_in[12];
    const float* WE   = (const float*)d_in[13];
    const float* bE   = (const float*)d_in[14];
    const float* bng  = (const float*)d_in[15];
    const float* bnb  = (const float*)d_in[16];
    const float* bnm  = (const float*)d_in[17];
    const float* bnv  = (const float*)d_in[18];
    const float* Wout = (const float*)d_in[19];
    const float* bout = (const float*)d_in[20];
    float* out = (float*)d_out;

    char* ws = (char*)d_ws;
    u16*   xT    = (u16*)  (ws + OFF_XT);
    u16*   P     = (u16*)  (ws + OFF_P);
    u16*   sVT   = (u16*)  (ws + OFF_SVT);
    u16*   AST   = (u16*)  (ws + OFF_AST);
    u16*   G     = (u16*)  (ws + OFF_G);
    u16*   H     = (u16*)  (ws + OFF_H);
    u16*   Zt    = (u16*)  (ws + OFF_ZT);
    u16*   ZSt   = (u16*)  (ws + OFF_ZST);
    u16*   Upad  = (u16*)  (ws + OFF_UPAD);
    u16*   Wcat  = (u16*)  (ws + OFF_WCAT);
    float* bcat  = (float*)(ws + OFF_BCAT);
    u16*   WEb   = (u16*)  (ws + OFF_WEB);
    u16*   Ws9   = (u16*)  (ws + OFF_WS9);
    float* scale = (float*)(ws + OFF_SCALE);
    float* shift = (float*)(ws + OFF_SHIFT);

    // 1. weight packing / bn fold
    prep_kernel<<<2048, 256, 0, stream>>>(WA, WB, WV, WAs, WBs, WVs,
                                          bA, bB, bV, bAs, bBs, bVs,
                                          WE, bng, bnb, bnm, bnv, Wout,
                                          Wcat, bcat, WEb, Ws9, scale, shift);

    // 2. xT[p][c] = bf16(x[c][p])
    transpose_kernel<float><<<dim3(98, 16, 8), 256, 0, stream>>>(
        x, xT, CIN, HW, (ll)CIN * HW, (ll)HW * CIN);

    // 3. fused projection: P[o][p] = Wcat[o][:] . xT[p][:] + bcat[o]
    gemm_bt_kernel<0><<<dim3(25, 5, 8), 256, 0, stream>>>(
        Wcat, CIN, 0, xT, CIN, (ll)HW * CIN, P, HW, (ll)MPROJ * HW,
        MPROJ, HW, CIN, bcat, nullptr, nullptr, nullptr, nullptr);

    // 4. softmax over spatial for B rows (128..191), in place
    softmax_rows_kernel<<<dim3(64, 8), 256, 0, stream>>>(P);

    // 5. channel softmax for V (192, n=64), B_S (384, 128), V_S (512, 128)
    softmax_cols_kernel<<<dim3(98, 3), 256, 0, stream>>>(P);

    // 6. transposes of softV and raw A_S
    transpose_kernel<u16><<<dim3(98, 2, 8), 256, 0, stream>>>(
        P + (ll)192 * HW, sVT, CN, HW, (ll)MPROJ * HW, (ll)HW * CN);
    transpose_kernel<u16><<<dim3(98, 4, 8), 256, 0, stream>>>(
        P + (ll)256 * HW, AST, CM, HW, (ll)MPROJ * HW, (ll)HW * CM);

    // 7. G[m][n] = A[m][:] . softB[n][:]     (K = 3136)
    gemm_bt_kernel<1><<<dim3(1, 1, 8), 256, 0, stream>>>(
        P, HW, (ll)MPROJ * HW, P + (ll)128 * HW, HW, (ll)MPROJ * HW,
        G, CN, (ll)CM * CN, CM, CN, HW,
        nullptr, nullptr, nullptr, nullptr, nullptr);

    // 8. H[m][m'] = softV_S[m][:] . softB_S[m'][:]
    gemm_bt_kernel<1><<<dim3(1, 1, 8), 256, 0, stream>>>(
        P + (ll)512 * HW, HW, (ll)MPROJ * HW, P + (ll)384 * HW, HW, (ll)MPROJ * HW,
        H, CM, (ll)CM * CM, CM, CM, HW,
        nullptr, nullptr, nullptr, nullptr, nullptr);

    // 9. Zt[p][m] = softVT[p][:] . G[m][:]   (K = 64)
    gemm_bt_kernel<1><<<dim3(1, 25, 8), 256, 0, stream>>>(
        sVT, CN, (ll)HW * CN, G, CN, (ll)CM * CN,
        Zt, CM, (ll)HW * CM, HW, CM, CN,
        nullptr, nullptr, nullptr, nullptr, nullptr);

    // 10. ZSt[p][m] = AST[p][:] . H[m][:]    (K = 128)
    gemm_bt_kernel<1><<<dim3(1, 25, 8), 256, 0, stream>>>(
        AST, CM, (ll)HW * CM, H, CM, (ll)CM * CM,
        ZSt, CM, (ll)HW * CM, HW, CM, CM,
        nullptr, nullptr, nullptr, nullptr, nullptr);

    // 11. zero padded residual buffer
    hipMemsetAsync(Upad, 0, (size_t)BATCH * UROWS * CIN * sizeof(u16), stream);

    // 12. E1 into UpadT: relu(bn(Zt . WE^T + bE))  (written at padded rows)
    gemm_bt_kernel<2><<<dim3(4, 25, 8), 256, 0, stream>>>(
        Zt, CM, (ll)HW * CM, WEb, CM, 0,
        Upad, CIN, (ll)UROWS * CIN, HW, CIN, CM,
        nullptr, bE, scale, shift, nullptr);

    // 13. E2 += : relu(bn(ZSt . WE^T + bE)) + E1 + x
    gemm_bt_kernel<3><<<dim3(4, 25, 8), 256, 0, stream>>>(
        ZSt, CM, (ll)HW * CM, WEb, CM, 0,
        Upad, CIN, (ll)UROWS * CIN, HW, CIN, CM,
        nullptr, bE, scale, shift, xT);

    // 14. 3x3 conv as 9 shift-GEMMs
    conv9_kernel<<<dim3(27, 4, 8), 256, 0, stream>>>(Ws9, Upad, bout, out);

    (void)in_sizes; (void)n_in; (void)out_size; (void)ws_size;
}

// Round 5
// 595.809 us; speedup vs baseline: 1.4141x; 1.4141x over previous
//
#include <hip/hip_runtime.h>

typedef short s16x8 __attribute__((ext_vector_type(8)));
typedef float f32x4 __attribute__((ext_vector_type(4)));
using u16 = unsigned short;
using ll = long long;

// ---------- bf16 helpers (bit-level, RNE) ----------
__device__ inline u16 f2b(float f) {
    union { float f; unsigned int i; } u; u.f = f;
    unsigned int r = u.i + 0x7FFFu + ((u.i >> 16) & 1u);
    return (u16)(r >> 16);
}
__device__ inline float b2f(u16 v) {
    union { unsigned int i; float f; } u; u.i = ((unsigned int)v) << 16; return u.f;
}

// global -> LDS async copy, 16B per lane. LDS dest must be wave-uniform base;
// lane l lands at base + l*16 bytes. [guide §5, m97/m104]
__device__ __forceinline__ void glds16(const u16* g, u16* lds) {
    __builtin_amdgcn_global_load_lds(
        (const __attribute__((address_space(1))) void*)g,
        (__attribute__((address_space(3))) void*)lds,
        16, 0, 0);
}

// ---------- problem constants ----------
#define BATCH 8
#define CIN   512
#define HW    3136   // 56*56
#define CM    128
#define CN    64
#define MPROJ 640    // 128+64+64+128+128+128
#define PADW  58
#define PADHW 3364   // 58*58
#define GUARD 64
#define UROWS (PADHW + 2*GUARD)  // 3492
#define GH_KS 7      // split-K factor for G/H (3136 = 7*448, 448 = 14*32)

// ws offsets (bytes)
#define OFF_XT     0LL                                 // [8][3136][512] bf16  25,690,112
#define OFF_P      25690112LL                          // [8][640][3136] bf16  32,112,640
#define OFF_SVT    57802752LL                          // [8][3136][64]  bf16   3,211,264
#define OFF_AST    61014016LL                          // [8][3136][128] bf16   6,422,528
#define OFF_G      67436544LL                          // [8][128][64]   bf16     131,072
#define OFF_H      67567616LL                          // [8][128][128]  bf16     262,144
#define OFF_ZT     67829760LL                          // [8][3136][128] bf16   6,422,528  (also partG f32 1.83MB)
#define OFF_ZST    74252288LL                          // [8][3136][128] bf16   6,422,528  (also partH f32 3.67MB)
#define OFF_UPAD   80674816LL                          // [8][3492][512] bf16  28,606,464
#define OFF_WCAT   109281280LL                         // [640][512] bf16         655,360
#define OFF_BCAT   109936640LL                         // [640] f32                 2,560
#define OFF_WEB    109939200LL                         // [512][128] bf16         131,072
#define OFF_WS9    110070272LL                         // [9][512][512] bf16    4,718,592
#define OFF_SCALE  114788864LL                         // [512] f32
#define OFF_SHIFT  114790912LL                         // [512] f32
#define WS_NEEDED  114792960LL

// ---------------------------------------------------------------------------
// prep: pack weights to bf16, fold bn. Ws9 repack: one thread per oc, 9
// contiguous reads (36B/thread, fully coalesced) -> 9 coalesced write streams.
// ---------------------------------------------------------------------------
__global__ void prep_kernel(
    const float* __restrict__ WA,  const float* __restrict__ WB,  const float* __restrict__ WV,
    const float* __restrict__ WAs, const float* __restrict__ WBs, const float* __restrict__ WVs,
    const float* __restrict__ bA,  const float* __restrict__ bB,  const float* __restrict__ bV,
    const float* __restrict__ bAs, const float* __restrict__ bBs, const float* __restrict__ bVs,
    const float* __restrict__ WE,  const float* __restrict__ bng, const float* __restrict__ bnb,
    const float* __restrict__ bnm, const float* __restrict__ bnv, const float* __restrict__ Wout,
    u16* __restrict__ Wcat, float* __restrict__ bcat, u16* __restrict__ WEb,
    u16* __restrict__ Ws9, float* __restrict__ scale, float* __restrict__ shift)
{
    ll tid = (ll)blockIdx.x * blockDim.x + threadIdx.x;
    ll stride = (ll)gridDim.x * blockDim.x;
    // Wcat rows: A 0..127 | B 128..191 | V 192..255 | A_S 256..383 | B_S 384..511 | V_S 512..639
    for (ll i = tid; i < (ll)MPROJ * CIN; i += stride) {
        int o = (int)(i / CIN), c = (int)(i % CIN);
        float v;
        if      (o < 128) v = WA [(o      )*CIN + c];
        else if (o < 192) v = WB [(o - 128)*CIN + c];
        else if (o < 256) v = WV [(o - 192)*CIN + c];
        else if (o < 384) v = WAs[(o - 256)*CIN + c];
        else if (o < 512) v = WBs[(o - 384)*CIN + c];
        else              v = WVs[(o - 512)*CIN + c];
        Wcat[i] = f2b(v);
    }
    for (ll i = tid; i < MPROJ; i += stride) {
        int o = (int)i; float v;
        if      (o < 128) v = bA [o];
        else if (o < 192) v = bB [o - 128];
        else if (o < 256) v = bV [o - 192];
        else if (o < 384) v = bAs[o - 256];
        else if (o < 512) v = bBs[o - 384];
        else              v = bVs[o - 512];
        bcat[i] = v;
    }
    for (ll i = tid; i < (ll)CIN * CM; i += stride) WEb[i] = f2b(WE[i]);
    for (ll oc = tid; oc < (ll)CIN * CIN; oc += stride) {
        #pragma unroll
        for (int s = 0; s < 9; ++s)
            Ws9[(ll)s * CIN * CIN + oc] = f2b(Wout[oc * 9 + s]);  // Wout[o][c][dy][dx] -> Ws9[s][o][c]
    }
    for (ll i = tid; i < CIN; i += stride) {
        float sc = bng[i] * rsqrtf(bnv[i] + 1e-5f);
        scale[i] = sc;
        shift[i] = bnb[i] - bnm[i] * sc;
    }
}

// ---------------------------------------------------------------------------
// transpose [R][C] -> [C][R], output bf16 (src fp32 or bf16). R,C mult of 32.
// ---------------------------------------------------------------------------
template<typename T>
__global__ __launch_bounds__(256) void transpose_kernel(
    const T* __restrict__ src, u16* __restrict__ dst,
    int R, int C, ll sS, ll sD)
{
    __shared__ u16 tile[32][33];
    int b  = blockIdx.z;
    int c0 = blockIdx.x << 5, r0 = blockIdx.y << 5;
    int tc = threadIdx.x & 31, tr = threadIdx.x >> 5;   // tr 0..7
    const T* s = src + sS * b;
    #pragma unroll
    for (int i = 0; i < 4; ++i) {
        int r = tr + i * 8;
        T v = s[(ll)(r0 + r) * C + c0 + tc];
        u16 u;
        if constexpr (sizeof(T) == 4) u = f2b((float)v);
        else                          u = (u16)v;
        tile[r][tc] = u;
    }
    __syncthreads();
    u16* d = dst + sD * b;
    #pragma unroll
    for (int i = 0; i < 4; ++i) {
        int c = tr + i * 8;
        d[(ll)(c0 + c) * R + r0 + tc] = tile[tc][c];
    }
}

// ---------------------------------------------------------------------------
// generic bf16 MFMA GEMM:  C[m,n] = sum_k A[m,k] * Bt[n,k]   (both row-major)
// BM=BN=128, BK=32, 256 thr = 4 waves (2x2), wave tile 64x64 = 4x4 frags.
// Staging via global_load_lds w16 into LINEAR [128][32] LDS tiles; OOB rows
// clamp to last valid row (duplicate data; OOB outputs discarded at epilogue).
// EPI: 0 = +rowBias -> bf16 C      (projection)
//      1 = plain -> bf16 C         (Zt / ZSt)
//      2 = +colBias, bn, relu -> write UpadT at remapped padded row
//      3 = same as 2 but += existing UpadT value += xT residual
// ---------------------------------------------------------------------------
template<int EPI>
__global__ __launch_bounds__(256) void gemm_bt_kernel(
    const u16* __restrict__ A, ll ldA, ll sA,
    const u16* __restrict__ Bt, ll ldB, ll sB,
    u16* __restrict__ C, ll ldC, ll sC,
    int M, int N, int K,
    const float* __restrict__ rowBias,
    const float* __restrict__ colBias,
    const float* __restrict__ scale,
    const float* __restrict__ shift,
    const u16* __restrict__ xT)
{
    __shared__ __align__(16) u16 As[128*32];
    __shared__ __align__(16) u16 Bs[128*32];
    const int b  = blockIdx.z;
    const int n0 = blockIdx.x * 128;
    const int m0 = blockIdx.y * 128;
    const int t  = threadIdx.x;
    const int lane = t & 63;
    const int w    = __builtin_amdgcn_readfirstlane(t >> 6);
    const int wm   = (w >> 1) * 64;
    const int wn   = (w & 1) * 64;
    const int l15  = lane & 15;
    const int hi   = lane >> 4;
    const int srow = lane >> 2;         // 0..15
    const int scol = (lane & 3) << 3;   // u16 units

    f32x4 acc[4][4];
    #pragma unroll
    for (int i = 0; i < 4; ++i)
        #pragma unroll
        for (int j = 0; j < 4; ++j) { acc[i][j][0]=0.f; acc[i][j][1]=0.f; acc[i][j][2]=0.f; acc[i][j][3]=0.f; }

    const u16* Ab = A  + sA * b;
    const u16* Bb = Bt + sB * b;
    const int nk = K >> 5;

    // per-lane staging rows (clamped to valid)
    const int ar0 = min(m0 + 32*w + srow,      M-1);
    const int ar1 = min(m0 + 32*w + 16 + srow, M-1);
    const int br0 = min(n0 + 32*w + srow,      N-1);
    const int br1 = min(n0 + 32*w + 16 + srow, N-1);
    u16* A0 = As + (32*w)*32;  u16* A1 = A0 + 16*32;
    u16* B0 = Bs + (32*w)*32;  u16* B1 = B0 + 16*32;

    for (int kc = 0; kc < nk; ++kc) {
        const int k0 = kc << 5;
        __syncthreads();
        glds16(Ab + (ll)ar0 * ldA + k0 + scol, A0);
        glds16(Ab + (ll)ar1 * ldA + k0 + scol, A1);
        glds16(Bb + (ll)br0 * ldB + k0 + scol, B0);
        glds16(Bb + (ll)br1 * ldB + k0 + scol, B1);
        __syncthreads();
        s16x8 af[4], bfr[4];
        #pragma unroll
        for (int i = 0; i < 4; ++i) {
            af[i]  = *(const s16x8*)(As + (wm + i*16 + l15)*32 + hi*8);
            bfr[i] = *(const s16x8*)(Bs + (wn + i*16 + l15)*32 + hi*8);
        }
        #pragma unroll
        for (int i = 0; i < 4; ++i)
            #pragma unroll
            for (int j = 0; j < 4; ++j)
                acc[i][j] = __builtin_amdgcn_mfma_f32_16x16x32_bf16(af[i], bfr[j], acc[i][j], 0, 0, 0);
    }

    // epilogue. D frag layout: col = lane&15, row = (lane>>4)*4 + r  [m89/m91]
    #pragma unroll
    for (int i = 0; i < 4; ++i) {
        #pragma unroll
        for (int j = 0; j < 4; ++j) {
            const int n = n0 + wn + j*16 + l15;
            if (n >= N) continue;
            #pragma unroll
            for (int r = 0; r < 4; ++r) {
                const int m = m0 + wm + i*16 + hi*4 + r;
                if (m >= M) continue;
                float v = acc[i][j][r];
                if constexpr (EPI == 0) {
                    v += rowBias[m];
                    C[sC*b + (ll)m*ldC + n] = f2b(v);
                } else if constexpr (EPI == 1) {
                    C[sC*b + (ll)m*ldC + n] = f2b(v);
                } else {
                    v += colBias[n];
                    v = v * scale[n] + shift[n];
                    v = fmaxf(v, 0.f);
                    const int y = m / 56, xx = m % 56;       // m is the pixel index
                    const ll  u = GUARD + (ll)(y + 1) * PADW + (xx + 1);
                    u16* dst = C + sC*b + u*ldC + n;
                    if constexpr (EPI == 2) {
                        *dst = f2b(v);
                    } else {
                        float prev = b2f(*dst);
                        float xv   = b2f(xT[((ll)b*HW + m)*CIN + n]);
                        *dst = f2b(v + prev + xv);
                    }
                }
            }
        }
    }
}

// ---------------------------------------------------------------------------
// split-K GEMM for G (128x64, K=3136) and H (128x128, K=3136).
// grid.x = 112: z<56 -> G chunk, z>=56 -> H chunk. Each block: one (batch,ks)
// chunk of 448 K (14 iters). f32 partials; reduced by reduce_gh_kernel.
// ---------------------------------------------------------------------------
__global__ __launch_bounds__(256) void gemm_gh_kernel(
    const u16* __restrict__ P, float* __restrict__ partG, float* __restrict__ partH)
{
    __shared__ __align__(16) u16 As[128*32];
    __shared__ __align__(16) u16 Bs[128*32];
    const int z   = blockIdx.x;
    const bool isH = (z >= 56);
    const int zz  = isH ? z - 56 : z;
    const int b   = zz / GH_KS, ks = zz % GH_KS;
    const int N   = isH ? 128 : 64;
    const u16* Ab = P + (ll)b*MPROJ*HW + (isH ? (ll)512*HW : 0LL);
    const u16* Bb = P + (ll)b*MPROJ*HW + (isH ? (ll)384*HW : (ll)128*HW);
    float* Cp = isH ? (partH + (ll)zz*CM*CM) : (partG + (ll)zz*CM*CN);

    const int t = threadIdx.x;
    const int lane = t & 63;
    const int w    = __builtin_amdgcn_readfirstlane(t >> 6);
    const int wm   = (w >> 1) * 64;
    const int wn   = (w & 1) * 64;
    const int l15  = lane & 15;
    const int hi   = lane >> 4;
    const int srow = lane >> 2;
    const int scol = (lane & 3) << 3;

    f32x4 acc[4][4];
    #pragma unroll
    for (int i = 0; i < 4; ++i)
        #pragma unroll
        for (int j = 0; j < 4; ++j) { acc[i][j][0]=0.f; acc[i][j][1]=0.f; acc[i][j][2]=0.f; acc[i][j][3]=0.f; }

    const int ar0 = 32*w + srow;            // M = 128 exact
    const int ar1 = ar0 + 16;
    const int br0 = min(32*w + srow,      N-1);
    const int br1 = min(32*w + 16 + srow, N-1);
    u16* A0 = As + (32*w)*32;  u16* A1 = A0 + 16*32;
    u16* B0 = Bs + (32*w)*32;  u16* B1 = B0 + 16*32;
    const int k0base = ks * (HW / GH_KS);   // 448*ks

    for (int kc = 0; kc < 14; ++kc) {
        const int k0 = k0base + (kc << 5);
        __syncthreads();
        glds16(Ab + (ll)ar0 * HW + k0 + scol, A0);
        glds16(Ab + (ll)ar1 * HW + k0 + scol, A1);
        glds16(Bb + (ll)br0 * HW + k0 + scol, B0);
        glds16(Bb + (ll)br1 * HW + k0 + scol, B1);
        __syncthreads();
        s16x8 af[4], bfr[4];
        #pragma unroll
        for (int i = 0; i < 4; ++i) {
            af[i]  = *(const s16x8*)(As + (wm + i*16 + l15)*32 + hi*8);
            bfr[i] = *(const s16x8*)(Bs + (wn + i*16 + l15)*32 + hi*8);
        }
        #pragma unroll
        for (int i = 0; i < 4; ++i)
            #pragma unroll
            for (int j = 0; j < 4; ++j)
                acc[i][j] = __builtin_amdgcn_mfma_f32_16x16x32_bf16(af[i], bfr[j], acc[i][j], 0, 0, 0);
    }

    #pragma unroll
    for (int i = 0; i < 4; ++i) {
        #pragma unroll
        for (int j = 0; j < 4; ++j) {
            const int n = wn + j*16 + l15;
            if (n >= N) continue;
            #pragma unroll
            for (int r = 0; r < 4; ++r) {
                const int m = wm + i*16 + hi*4 + r;
                Cp[(ll)m * N + n] = acc[i][j][r];
            }
        }
    }
}

__global__ void reduce_gh_kernel(const float* __restrict__ pg, const float* __restrict__ ph,
                                 u16* __restrict__ G, u16* __restrict__ H)
{
    int i = blockIdx.x * 256 + threadIdx.x;
    if (i < BATCH*CM*CN) {
        int b = i / (CM*CN), r = i % (CM*CN);
        float s = 0.f;
        #pragma unroll
        for (int ks = 0; ks < GH_KS; ++ks) s += pg[(ll)(b*GH_KS+ks)*CM*CN + r];
        G[(ll)b*CM*CN + r] = f2b(s);
    } else {
        int j = i - BATCH*CM*CN;
        if (j < BATCH*CM*CM) {
            int b = j / (CM*CM), r = j % (CM*CM);
            float s = 0.f;
            #pragma unroll
            for (int ks = 0; ks < GH_KS; ++ks) s += ph[(ll)(b*GH_KS+ks)*CM*CM + r];
            H[(ll)b*CM*CM + r] = f2b(s);
        }
    }
}

// ---------------------------------------------------------------------------
// softmax over spatial (3136) for the 64 B-rows of P, in place (bf16)
// ---------------------------------------------------------------------------
__global__ __launch_bounds__(256) void softmax_rows_kernel(u16* __restrict__ P)
{
    __shared__ float red[4];
    __shared__ float red2[4];
    const int b = blockIdx.y, row = 128 + blockIdx.x;
    u16* p = P + ((ll)b * MPROJ + row) * HW;
    const int t = threadIdx.x;
    float vals[13];
    int cnt = 0;
    float m = -1e30f;
    for (int j = t; j < HW; j += 256) { float v = b2f(p[j]); vals[cnt++] = v; m = fmaxf(m, v); }
    #pragma unroll
    for (int o = 32; o; o >>= 1) m = fmaxf(m, __shfl_xor(m, o));
    const int wid = t >> 6;
    if ((t & 63) == 0) red[wid] = m;
    __syncthreads();
    m = fmaxf(fmaxf(red[0], red[1]), fmaxf(red[2], red[3]));
    float s = 0.f;
    for (int i = 0; i < cnt; ++i) { vals[i] = __expf(vals[i] - m); s += vals[i]; }
    #pragma unroll
    for (int o = 32; o; o >>= 1) s += __shfl_xor(s, o);
    if ((t & 63) == 0) red2[wid] = s;
    __syncthreads();
    s = red2[0] + red2[1] + red2[2] + red2[3];
    const float inv = 1.f / s;
    cnt = 0;
    for (int j = t; j < HW; j += 256) p[j] = f2b(vals[cnt++] * inv);
}

// ---------------------------------------------------------------------------
// channel softmax (over 64 or 128 rows) per pixel, in place.
// grid.y selects group: 0 = V(192,64) 1 = B_S(384,128) 2 = V_S(512,128)
// ---------------------------------------------------------------------------
__global__ void softmax_cols_kernel(u16* __restrict__ P)
{
    int idx = blockIdx.x * 256 + threadIdx.x;
    if (idx >= BATCH * HW) return;
    const int b = idx / HW, p = idx % HW;
    int off, n;
    if      (blockIdx.y == 0) { off = 192; n = 64;  }
    else if (blockIdx.y == 1) { off = 384; n = 128; }
    else                      { off = 512; n = 128; }
    u16* g = P + (ll)b * MPROJ * HW + (ll)off * HW + p;
    float m = -1e30f, s = 0.f;
    for (int i = 0; i < n; ++i) {
        float v  = b2f(g[(ll)i * HW]);
        float nm = fmaxf(m, v);
        s = s * __expf(m - nm) + __expf(v - nm);
        m = nm;
    }
    const float inv = 1.f / s;
    for (int i = 0; i < n; ++i) {
        const ll o = (ll)i * HW;
        g[o] = f2b(__expf(b2f(g[o]) - m) * inv);
    }
}

// ---------------------------------------------------------------------------
// conv3x3 as 9 shift-GEMMs over padded pixel domain, global_load_lds staging,
// XCD-swizzled 1-D grid: 864 blocks = 8 XCDs x 108; each XCD's chunk shares
// one Ws9 m-tile (1.18MB -> L2-resident) and 4 batch images.
// ---------------------------------------------------------------------------
__global__ __launch_bounds__(256) void conv9_kernel(
    const u16* __restrict__ Ws9, const u16* __restrict__ UpadT,
    const float* __restrict__ bout, float* __restrict__ out)
{
    __shared__ __align__(16) u16 As[128*32];
    __shared__ __align__(16) u16 Bs[128*32];
    const int id  = blockIdx.x;                 // 0..863
    const int lid = (id & 7) * 108 + (id >> 3); // logical id, contiguous per XCD
    const int mt  = lid / 216;                  // 4 m-tiles, 216 blocks each
    const int r1  = lid % 216;
    const int b   = r1 / 27;                    // batch
    const int nt  = r1 % 27;                    // n-tile
    const int m0 = mt << 7, n0 = nt << 7;

    const int t = threadIdx.x;
    const int lane = t & 63;
    const int w    = __builtin_amdgcn_readfirstlane(t >> 6);
    const int wm   = (w >> 1) * 64;
    const int wn   = (w & 1) * 64;
    const int l15  = lane & 15;
    const int hi   = lane >> 4;
    const int srow = lane >> 2;
    const int scol = (lane & 3) << 3;

    f32x4 acc[4][4];
    #pragma unroll
    for (int i = 0; i < 4; ++i)
        #pragma unroll
        for (int j = 0; j < 4; ++j) { acc[i][j][0]=0.f; acc[i][j][1]=0.f; acc[i][j][2]=0.f; acc[i][j][3]=0.f; }

    const u16* Ub = UpadT + (ll)b * UROWS * CIN;
    const int ar0 = m0 + 32*w + srow;        // <= 511, always valid
    const int ar1 = ar0 + 16;
    const int nb0 = n0 + 32*w + srow;
    u16* A0 = As + (32*w)*32;  u16* A1 = A0 + 16*32;
    u16* B0 = Bs + (32*w)*32;  u16* B1 = B0 + 16*32;

    for (int s = 0; s < 9; ++s) {
        const int doff = (s / 3 - 1) * PADW + (s % 3 - 1);
        const u16* Ab = Ws9 + (ll)s * CIN * CIN;
        const int u0 = min(GUARD + nb0 + doff,      UROWS - 1);  // >= 5
        const int u1 = min(GUARD + nb0 + 16 + doff, UROWS - 1);
        for (int kc = 0; kc < 16; ++kc) {
            const int k0 = kc << 5;
            __syncthreads();
            glds16(Ab + (ll)ar0 * CIN + k0 + scol, A0);
            glds16(Ab + (ll)ar1 * CIN + k0 + scol, A1);
            glds16(Ub + (ll)u0 * CIN + k0 + scol, B0);
            glds16(Ub + (ll)u1 * CIN + k0 + scol, B1);
            __syncthreads();
            s16x8 af[4], bfr[4];
            #pragma unroll
            for (int i = 0; i < 4; ++i) {
                af[i]  = *(const s16x8*)(As + (wm + i*16 + l15)*32 + hi*8);
                bfr[i] = *(const s16x8*)(Bs + (wn + i*16 + l15)*32 + hi*8);
            }
            #pragma unroll
            for (int i = 0; i < 4; ++i)
                #pragma unroll
                for (int j = 0; j < 4; ++j)
                    acc[i][j] = __builtin_amdgcn_mfma_f32_16x16x32_bf16(af[i], bfr[j], acc[i][j], 0, 0, 0);
        }
    }

    #pragma unroll
    for (int i = 0; i < 4; ++i) {
        #pragma unroll
        for (int j = 0; j < 4; ++j) {
            const int pc = n0 + wn + j*16 + l15;       // padded pixel index
            const int y = pc / PADW, xx = pc % PADW;
            if (y >= 1 && y <= 56 && xx >= 1 && xx <= 56) {
                const int p = (y - 1) * 56 + (xx - 1);
                #pragma unroll
                for (int r = 0; r < 4; ++r) {
                    const int m = m0 + wm + i*16 + hi*4 + r;
                    out[((ll)b * CIN + m) * HW + p] = acc[i][j][r] + bout[m];
                }
            }
        }
    }
}

// ---------------------------------------------------------------------------
extern "C" void kernel_launch(void* const* d_in, const int* in_sizes, int n_in,
                              void* d_out, int out_size, void* d_ws, size_t ws_size,
                              hipStream_t stream)
{
    const float* x    = (const float*)d_in[0];
    const float* WA   = (const float*)d_in[1];
    const float* bA   = (const float*)d_in[2];
    const float* WB   = (const float*)d_in[3];
    const float* bB   = (const float*)d_in[4];
    const float* WV   = (const float*)d_in[5];
    const float* bV   = (const float*)d_in[6];
    const float* WAs  = (const float*)d_in[7];
    const float* bAs  = (const float*)d_in[8];
    const float* WBs  = (const float*)d_in[9];
    const float* bBs  = (const float*)d_in[10];
    const float* WVs  = (const float*)d_in[11];
    const float* bVs  = (const float*)d_in[12];
    const float* WE   = (const float*)d_in[13];
    const float* bE   = (const float*)d_in[14];
    const float* bng  = (const float*)d_in[15];
    const float* bnb  = (const float*)d_in[16];
    const float* bnm  = (const float*)d_in[17];
    const float* bnv  = (const float*)d_in[18];
    const float* Wout = (const float*)d_in[19];
    const float* bout = (const float*)d_in[20];
    float* out = (float*)d_out;

    char* ws = (char*)d_ws;
    u16*   xT    = (u16*)  (ws + OFF_XT);
    u16*   P     = (u16*)  (ws + OFF_P);
    u16*   sVT   = (u16*)  (ws + OFF_SVT);
    u16*   AST   = (u16*)  (ws + OFF_AST);
    u16*   G     = (u16*)  (ws + OFF_G);
    u16*   H     = (u16*)  (ws + OFF_H);
    u16*   Zt    = (u16*)  (ws + OFF_ZT);
    u16*   ZSt   = (u16*)  (ws + OFF_ZST);
    float* partG = (float*)(ws + OFF_ZT);    // transient, consumed before Zt written
    float* partH = (float*)(ws + OFF_ZST);   // transient, consumed before ZSt written
    u16*   Upad  = (u16*)  (ws + OFF_UPAD);
    u16*   Wcat  = (u16*)  (ws + OFF_WCAT);
    float* bcat  = (float*)(ws + OFF_BCAT);
    u16*   WEb   = (u16*)  (ws + OFF_WEB);
    u16*   Ws9   = (u16*)  (ws + OFF_WS9);
    float* scale = (float*)(ws + OFF_SCALE);
    float* shift = (float*)(ws + OFF_SHIFT);

    // 1. weight packing / bn fold
    prep_kernel<<<2048, 256, 0, stream>>>(WA, WB, WV, WAs, WBs, WVs,
                                          bA, bB, bV, bAs, bBs, bVs,
                                          WE, bng, bnb, bnm, bnv, Wout,
                                          Wcat, bcat, WEb, Ws9, scale, shift);

    // 2. xT[p][c] = bf16(x[c][p])
    transpose_kernel<float><<<dim3(98, 16, 8), 256, 0, stream>>>(
        x, xT, CIN, HW, (ll)CIN * HW, (ll)HW * CIN);

    // 3. fused projection: P[o][p] = Wcat[o][:] . xT[p][:] + bcat[o]
    gemm_bt_kernel<0><<<dim3(25, 5, 8), 256, 0, stream>>>(
        Wcat, CIN, 0, xT, CIN, (ll)HW * CIN, P, HW, (ll)MPROJ * HW,
        MPROJ, HW, CIN, bcat, nullptr, nullptr, nullptr, nullptr);

    // 4. softmax over spatial for B rows (128..191), in place
    softmax_rows_kernel<<<dim3(64, 8), 256, 0, stream>>>(P);

    // 5. channel softmax for V (192, n=64), B_S (384, 128), V_S (512, 128)
    softmax_cols_kernel<<<dim3(98, 3), 256, 0, stream>>>(P);

    // 6. transposes of softV and raw A_S
    transpose_kernel<u16><<<dim3(98, 2, 8), 256, 0, stream>>>(
        P + (ll)192 * HW, sVT, CN, HW, (ll)MPROJ * HW, (ll)HW * CN);
    transpose_kernel<u16><<<dim3(98, 4, 8), 256, 0, stream>>>(
        P + (ll)256 * HW, AST, CM, HW, (ll)MPROJ * HW, (ll)HW * CM);

    // 7. G = A . softB^T and H = softV_S . softB_S^T via 7-way split-K
    gemm_gh_kernel<<<112, 256, 0, stream>>>(P, partG, partH);
    reduce_gh_kernel<<<768, 256, 0, stream>>>(partG, partH, G, H);

    // 9. Zt[p][m] = softVT[p][:] . G[m][:]   (K = 64)
    gemm_bt_kernel<1><<<dim3(1, 25, 8), 256, 0, stream>>>(
        sVT, CN, (ll)HW * CN, G, CN, (ll)CM * CN,
        Zt, CM, (ll)HW * CM, HW, CM, CN,
        nullptr, nullptr, nullptr, nullptr, nullptr);

    // 10. ZSt[p][m] = AST[p][:] . H[m][:]    (K = 128)
    gemm_bt_kernel<1><<<dim3(1, 25, 8), 256, 0, stream>>>(
        AST, CM, (ll)HW * CM, H, CM, (ll)CM * CM,
        ZSt, CM, (ll)HW * CM, HW, CM, CM,
        nullptr, nullptr, nullptr, nullptr, nullptr);

    // 11. zero padded residual buffer
    hipMemsetAsync(Upad, 0, (size_t)BATCH * UROWS * CIN * sizeof(u16), stream);

    // 12. E1 into UpadT: relu(bn(Zt . WE^T + bE))  (written at padded rows)
    gemm_bt_kernel<2><<<dim3(4, 25, 8), 256, 0, stream>>>(
        Zt, CM, (ll)HW * CM, WEb, CM, 0,
        Upad, CIN, (ll)UROWS * CIN, HW, CIN, CM,
        nullptr, bE, scale, shift, nullptr);

    // 13. E2 += : relu(bn(ZSt . WE^T + bE)) + E1 + x
    gemm_bt_kernel<3><<<dim3(4, 25, 8), 256, 0, stream>>>(
        ZSt, CM, (ll)HW * CM, WEb, CM, 0,
        Upad, CIN, (ll)UROWS * CIN, HW, CIN, CM,
        nullptr, bE, scale, shift, xT);

    // 14. 3x3 conv as 9 shift-GEMMs (XCD-swizzled 1-D grid)
    conv9_kernel<<<864, 256, 0, stream>>>(Ws9, Upad, bout, out);

    (void)in_sizes; (void)n_in; (void)out_size; (void)ws_size;
}

// Round 7
// 535.764 us; speedup vs baseline: 1.5725x; 1.1121x over previous
//
#include <hip/hip_runtime.h>

typedef short s16x8 __attribute__((ext_vector_type(8)));
typedef float f32x4 __attribute__((ext_vector_type(4)));
using u16 = unsigned short;
using ll = long long;

// ---------- bf16 helpers (bit-level, RNE) ----------
__device__ inline u16 f2b(float f) {
    union { float f; unsigned int i; } u; u.f = f;
    unsigned int r = u.i + 0x7FFFu + ((u.i >> 16) & 1u);
    return (u16)(r >> 16);
}
__device__ inline float b2f(u16 v) {
    union { unsigned int i; float f; } u; u.i = ((unsigned int)v) << 16; return u.f;
}

// global -> LDS async copy, 16B per lane. LDS dest wave-uniform base; lane l
// lands at base + l*16 bytes. [guide §5, m97/m104]
__device__ __forceinline__ void glds16(const u16* g, u16* lds) {
    __builtin_amdgcn_global_load_lds(
        (const __attribute__((address_space(1))) void*)g,
        (__attribute__((address_space(3))) void*)lds,
        16, 0, 0);
}

// ---------- problem constants ----------
#define BATCH 8
#define CIN   512
#define HW    3136   // 56*56
#define CM    128
#define CN    64
#define MPROJ 640
#define PADW  58
#define PADHW 3364   // 58*58
#define GUARD 64
#define UROWS (PADHW + 2*GUARD)  // 3492
#define GH_KS 7      // split-K for G/H (3136 = 7*448)

// ws offsets (bytes)
#define OFF_XT     0LL                                 // [8][3136][512] bf16
#define OFF_P      25690112LL                          // [8][640][3136] bf16
#define OFF_SAT    57802752LL                          // [8][3136][192] bf16 (9.63MB)
#define OFF_GHT    67436544LL                          // [8][192][128]  bf16 (393KB)
#define OFF_ZT     67829760LL                          // partG f32 / then WGHT [8][512][192] bf16
#define OFF_ZST    74252288LL                          // partH f32 (transient)
#define OFF_UPAD   80674816LL                          // [8][3492][512] bf16
#define OFF_WCAT   109281280LL                         // [640][512] bf16
#define OFF_BCAT   109936640LL                         // [640] f32
#define OFF_WEB    109939200LL                         // [512][128] bf16
#define OFF_WS9    110070272LL                         // Ws9f frag-ordered [4][9][16][8][64][8] bf16
#define OFF_SCALE  114788864LL
#define OFF_SHIFT  114790912LL

// ---------------------------------------------------------------------------
// prep: pack weights to bf16, fold bn. Ws9f: Wout permuted into MFMA A-frag
// order [mt][s][kc][mb][lane64][8e] so conv9 A-loads are 1KB coalesced.
// ---------------------------------------------------------------------------
__global__ void prep_kernel(
    const float* __restrict__ WA,  const float* __restrict__ WB,  const float* __restrict__ WV,
    const float* __restrict__ WAs, const float* __restrict__ WBs, const float* __restrict__ WVs,
    const float* __restrict__ bA,  const float* __restrict__ bB,  const float* __restrict__ bV,
    const float* __restrict__ bAs, const float* __restrict__ bBs, const float* __restrict__ bVs,
    const float* __restrict__ WE,  const float* __restrict__ bng, const float* __restrict__ bnb,
    const float* __restrict__ bnm, const float* __restrict__ bnv, const float* __restrict__ Wout,
    u16* __restrict__ Wcat, float* __restrict__ bcat, u16* __restrict__ WEb,
    u16* __restrict__ Ws9f, float* __restrict__ scale, float* __restrict__ shift)
{
    ll tid = (ll)blockIdx.x * blockDim.x + threadIdx.x;
    ll stride = (ll)gridDim.x * blockDim.x;
    // Wcat rows: A 0..127 | B 128..191 | V 192..255 | A_S 256..383 | B_S 384..511 | V_S 512..639
    for (ll i = tid; i < (ll)MPROJ * CIN; i += stride) {
        int o = (int)(i / CIN), c = (int)(i % CIN);
        float v;
        if      (o < 128) v = WA [(o      )*CIN + c];
        else if (o < 192) v = WB [(o - 128)*CIN + c];
        else if (o < 256) v = WV [(o - 192)*CIN + c];
        else if (o < 384) v = WAs[(o - 256)*CIN + c];
        else if (o < 512) v = WBs[(o - 384)*CIN + c];
        else              v = WVs[(o - 512)*CIN + c];
        Wcat[i] = f2b(v);
    }
    for (ll i = tid; i < MPROJ; i += stride) {
        int o = (int)i; float v;
        if      (o < 128) v = bA [o];
        else if (o < 192) v = bB [o - 128];
        else if (o < 256) v = bV [o - 192];
        else if (o < 384) v = bAs[o - 256];
        else if (o < 512) v = bBs[o - 384];
        else              v = bVs[o - 512];
        bcat[i] = v;
    }
    for (ll i = tid; i < (ll)CIN * CM; i += stride) WEb[i] = f2b(WE[i]);
    // Ws9f[mt][s][kc][mb][lane][e]: lane = hic*16 + (o&15); covers (row o, chans kc*32+hic*8+e)
    for (ll oc = tid; oc < (ll)CIN * CIN; oc += stride) {
        int o = (int)(oc >> 9), c = (int)(oc & 511);
        int mt = o >> 7, mb = (o >> 4) & 7, lo = o & 15;
        int kc = c >> 5, hic = (c >> 3) & 3, e = c & 7;
        #pragma unroll
        for (int s = 0; s < 9; ++s) {
            ll idx = ((((ll)(mt*9 + s)*16 + kc)*8 + mb)*64 + hic*16 + lo)*8 + e;
            Ws9f[idx] = f2b(Wout[oc * 9 + s]);
        }
    }
    for (ll i = tid; i < CIN; i += stride) {
        float sc = bng[i] * rsqrtf(bnv[i] + 1e-5f);
        scale[i] = sc;
        shift[i] = bnb[i] - bnm[i] * sc;
    }
}

// ---------------------------------------------------------------------------
// transpose [R][C] -> dst[c][ldD..]: dst[c*ldD + dcol + r]. R,C mult of 32.
// ---------------------------------------------------------------------------
template<typename T>
__global__ __launch_bounds__(256) void transpose_kernel(
    const T* __restrict__ src, u16* __restrict__ dst,
    int R, int C, ll sS, ll sD, int ldD, int dcol)
{
    __shared__ u16 tile[32][33];
    int b  = blockIdx.z;
    int c0 = blockIdx.x << 5, r0 = blockIdx.y << 5;
    int tc = threadIdx.x & 31, tr = threadIdx.x >> 5;
    const T* s = src + sS * b;
    #pragma unroll
    for (int i = 0; i < 4; ++i) {
        int r = tr + i * 8;
        T v = s[(ll)(r0 + r) * C + c0 + tc];
        u16 u;
        if constexpr (sizeof(T) == 4) u = f2b((float)v);
        else                          u = (u16)v;
        tile[r][tc] = u;
    }
    __syncthreads();
    u16* d = dst + sD * b;
    #pragma unroll
    for (int i = 0; i < 4; ++i) {
        int c = tr + i * 8;
        d[(ll)(c0 + c) * ldD + dcol + r0 + tc] = tile[tc][c];
    }
}

// ---------------------------------------------------------------------------
// generic bf16 MFMA GEMM:  C[m,n] = sum_k A[m,k] * Bt[n,k]
// EPI: 0 = +rowBias -> bf16 C   1 = plain -> bf16 C
// ---------------------------------------------------------------------------
template<int EPI>
__global__ __launch_bounds__(256) void gemm_bt_kernel(
    const u16* __restrict__ A, ll ldA, ll sA,
    const u16* __restrict__ Bt, ll ldB, ll sB,
    u16* __restrict__ C, ll ldC, ll sC,
    int M, int N, int K,
    const float* __restrict__ rowBias)
{
    __shared__ __align__(16) u16 As[128*32];
    __shared__ __align__(16) u16 Bs[128*32];
    const int b  = blockIdx.z;
    const int n0 = blockIdx.x * 128;
    const int m0 = blockIdx.y * 128;
    const int t  = threadIdx.x;
    const int lane = t & 63;
    const int w    = __builtin_amdgcn_readfirstlane(t >> 6);
    const int wm   = (w >> 1) * 64;
    const int wn   = (w & 1) * 64;
    const int l15  = lane & 15;
    const int hi   = lane >> 4;
    const int srow = lane >> 2;
    const int scol = (lane & 3) << 3;

    f32x4 acc[4][4];
    #pragma unroll
    for (int i = 0; i < 4; ++i)
        #pragma unroll
        for (int j = 0; j < 4; ++j) { acc[i][j][0]=0.f; acc[i][j][1]=0.f; acc[i][j][2]=0.f; acc[i][j][3]=0.f; }

    const u16* Ab = A  + sA * b;
    const u16* Bb = Bt + sB * b;
    const int nk = K >> 5;

    const int ar0 = min(m0 + 32*w + srow,      M-1);
    const int ar1 = min(m0 + 32*w + 16 + srow, M-1);
    const int br0 = min(n0 + 32*w + srow,      N-1);
    const int br1 = min(n0 + 32*w + 16 + srow, N-1);
    u16* A0 = As + (32*w)*32;  u16* A1 = A0 + 16*32;
    u16* B0 = Bs + (32*w)*32;  u16* B1 = B0 + 16*32;

    for (int kc = 0; kc < nk; ++kc) {
        const int k0 = kc << 5;
        __syncthreads();
        glds16(Ab + (ll)ar0 * ldA + k0 + scol, A0);
        glds16(Ab + (ll)ar1 * ldA + k0 + scol, A1);
        glds16(Bb + (ll)br0 * ldB + k0 + scol, B0);
        glds16(Bb + (ll)br1 * ldB + k0 + scol, B1);
        __syncthreads();
        s16x8 af[4], bfr[4];
        #pragma unroll
        for (int i = 0; i < 4; ++i) {
            af[i]  = *(const s16x8*)(As + (wm + i*16 + l15)*32 + hi*8);
            bfr[i] = *(const s16x8*)(Bs + (wn + i*16 + l15)*32 + hi*8);
        }
        #pragma unroll
        for (int i = 0; i < 4; ++i)
            #pragma unroll
            for (int j = 0; j < 4; ++j)
                acc[i][j] = __builtin_amdgcn_mfma_f32_16x16x32_bf16(af[i], bfr[j], acc[i][j], 0, 0, 0);
    }

    #pragma unroll
    for (int i = 0; i < 4; ++i) {
        #pragma unroll
        for (int j = 0; j < 4; ++j) {
            const int n = n0 + wn + j*16 + l15;
            if (n >= N) continue;
            #pragma unroll
            for (int r = 0; r < 4; ++r) {
                const int m = m0 + wm + i*16 + hi*4 + r;
                if (m >= M) continue;
                float v = acc[i][j][r];
                if constexpr (EPI == 0) v += rowBias[m];
                C[sC*b + (ll)m*ldC + n] = f2b(v);
            }
        }
    }
}

// ---------------------------------------------------------------------------
// split-K GEMM for G (128x64 K=3136) and H (128x128 K=3136) partials
// ---------------------------------------------------------------------------
__global__ __launch_bounds__(256) void gemm_gh_kernel(
    const u16* __restrict__ P, float* __restrict__ partG, float* __restrict__ partH)
{
    __shared__ __align__(16) u16 As[128*32];
    __shared__ __align__(16) u16 Bs[128*32];
    const int z   = blockIdx.x;
    const bool isH = (z >= 56);
    const int zz  = isH ? z - 56 : z;
    const int b   = zz / GH_KS, ks = zz % GH_KS;
    const int N   = isH ? 128 : 64;
    const u16* Ab = P + (ll)b*MPROJ*HW + (isH ? (ll)512*HW : 0LL);
    const u16* Bb = P + (ll)b*MPROJ*HW + (isH ? (ll)384*HW : (ll)128*HW);
    float* Cp = isH ? (partH + (ll)zz*CM*CM) : (partG + (ll)zz*CM*CN);

    const int t = threadIdx.x;
    const int lane = t & 63;
    const int w    = __builtin_amdgcn_readfirstlane(t >> 6);
    const int wm   = (w >> 1) * 64;
    const int wn   = (w & 1) * 64;
    const int l15  = lane & 15;
    const int hi   = lane >> 4;
    const int srow = lane >> 2;
    const int scol = (lane & 3) << 3;

    f32x4 acc[4][4];
    #pragma unroll
    for (int i = 0; i < 4; ++i)
        #pragma unroll
        for (int j = 0; j < 4; ++j) { acc[i][j][0]=0.f; acc[i][j][1]=0.f; acc[i][j][2]=0.f; acc[i][j][3]=0.f; }

    const int ar0 = 32*w + srow;
    const int ar1 = ar0 + 16;
    const int br0 = min(32*w + srow,      N-1);
    const int br1 = min(32*w + 16 + srow, N-1);
    u16* A0 = As + (32*w)*32;  u16* A1 = A0 + 16*32;
    u16* B0 = Bs + (32*w)*32;  u16* B1 = B0 + 16*32;
    const int k0base = ks * (HW / GH_KS);

    for (int kc = 0; kc < 14; ++kc) {
        const int k0 = k0base + (kc << 5);
        __syncthreads();
        glds16(Ab + (ll)ar0 * HW + k0 + scol, A0);
        glds16(Ab + (ll)ar1 * HW + k0 + scol, A1);
        glds16(Bb + (ll)br0 * HW + k0 + scol, B0);
        glds16(Bb + (ll)br1 * HW + k0 + scol, B1);
        __syncthreads();
        s16x8 af[4], bfr[4];
        #pragma unroll
        for (int i = 0; i < 4; ++i) {
            af[i]  = *(const s16x8*)(As + (wm + i*16 + l15)*32 + hi*8);
            bfr[i] = *(const s16x8*)(Bs + (wn + i*16 + l15)*32 + hi*8);
        }
        #pragma unroll
        for (int i = 0; i < 4; ++i)
            #pragma unroll
            for (int j = 0; j < 4; ++j)
                acc[i][j] = __builtin_amdgcn_mfma_f32_16x16x32_bf16(af[i], bfr[j], acc[i][j], 0, 0, 0);
    }

    #pragma unroll
    for (int i = 0; i < 4; ++i) {
        #pragma unroll
        for (int j = 0; j < 4; ++j) {
            const int n = wn + j*16 + l15;
            if (n >= N) continue;
            #pragma unroll
            for (int r = 0; r < 4; ++r) {
                const int m = wm + i*16 + hi*4 + r;
                Cp[(ll)m * N + n] = acc[i][j][r];
            }
        }
    }
}

// reduce partials -> GHT[b][192][128]: rows 0..63 = G^T, rows 64..191 = H^T
__global__ void reduce_gh_kernel(const float* __restrict__ pg, const float* __restrict__ ph,
                                 u16* __restrict__ GHT)
{
    int i = blockIdx.x * 256 + threadIdx.x;
    if (i < BATCH*CM*CN) {
        int b = i / (CM*CN), r = i % (CM*CN);
        int m = r / CN, n = r % CN;
        float s = 0.f;
        #pragma unroll
        for (int ks = 0; ks < GH_KS; ++ks) s += pg[(ll)(b*GH_KS+ks)*CM*CN + r];
        GHT[(ll)b*192*128 + (ll)n*128 + m] = f2b(s);
    } else {
        int j = i - BATCH*CM*CN;
        if (j < BATCH*CM*CM) {
            int b = j / (CM*CM), r = j % (CM*CM);
            int m = r / CM, mp = r % CM;
            float s = 0.f;
            #pragma unroll
            for (int ks = 0; ks < GH_KS; ++ks) s += ph[(ll)(b*GH_KS+ks)*CM*CM + r];
            GHT[(ll)b*192*128 + (ll)(64+mp)*128 + m] = f2b(s);
        }
    }
}

// ---------------------------------------------------------------------------
// softmax over spatial (3136) for the 64 B-rows of P, in place
// ---------------------------------------------------------------------------
__global__ __launch_bounds__(256) void softmax_rows_kernel(u16* __restrict__ P)
{
    __shared__ float red[4];
    __shared__ float red2[4];
    const int b = blockIdx.y, row = 128 + blockIdx.x;
    u16* p = P + ((ll)b * MPROJ + row) * HW;
    const int t = threadIdx.x;
    float vals[13];
    int cnt = 0;
    float m = -1e30f;
    for (int j = t; j < HW; j += 256) { float v = b2f(p[j]); vals[cnt++] = v; m = fmaxf(m, v); }
    #pragma unroll
    for (int o = 32; o; o >>= 1) m = fmaxf(m, __shfl_xor(m, o));
    const int wid = t >> 6;
    if ((t & 63) == 0) red[wid] = m;
    __syncthreads();
    m = fmaxf(fmaxf(red[0], red[1]), fmaxf(red[2], red[3]));
    float s = 0.f;
    for (int i = 0; i < cnt; ++i) { vals[i] = __expf(vals[i] - m); s += vals[i]; }
    #pragma unroll
    for (int o = 32; o; o >>= 1) s += __shfl_xor(s, o);
    if ((t & 63) == 0) red2[wid] = s;
    __syncthreads();
    s = red2[0] + red2[1] + red2[2] + red2[3];
    const float inv = 1.f / s;
    cnt = 0;
    for (int j = t; j < HW; j += 256) p[j] = f2b(vals[cnt++] * inv);
}

// ---------------------------------------------------------------------------
// channel softmax per pixel in place: 0=V(192,64) 1=B_S(384,128) 2=V_S(512,128)
// ---------------------------------------------------------------------------
__global__ void softmax_cols_kernel(u16* __restrict__ P)
{
    int idx = blockIdx.x * 256 + threadIdx.x;
    if (idx >= BATCH * HW) return;
    const int b = idx / HW, p = idx % HW;
    int off, n;
    if      (blockIdx.y == 0) { off = 192; n = 64;  }
    else if (blockIdx.y == 1) { off = 384; n = 128; }
    else                      { off = 512; n = 128; }
    u16* g = P + (ll)b * MPROJ * HW + (ll)off * HW + p;
    float m = -1e30f, s = 0.f;
    for (int i = 0; i < n; ++i) {
        float v  = b2f(g[(ll)i * HW]);
        float nm = fmaxf(m, v);
        s = s * __expf(m - nm) + __expf(v - nm);
        m = nm;
    }
    const float inv = 1.f / s;
    for (int i = 0; i < n; ++i) {
        const ll o = (ll)i * HW;
        g[o] = f2b(__expf(b2f(g[o]) - m) * inv);
    }
}

// ---------------------------------------------------------------------------
// e12: C[p][cout] dual-accumulator GEMM over SAT[3136][192] x WGHT[512][192]:
// kc 0..1 -> acc1 (E1pre), kc 2..5 -> acc2 (E2pre); epilogue applies
// relu(bn(.+bE)) to each, sums, adds x residual, writes Upad interior once.
// ---------------------------------------------------------------------------
__global__ __launch_bounds__(256) void e12_kernel(
    const u16* __restrict__ SAT, const u16* __restrict__ WGHT,
    const u16* __restrict__ xT,  const float* __restrict__ bE,
    const float* __restrict__ scale, const float* __restrict__ shift,
    u16* __restrict__ Upad)
{
    __shared__ __align__(16) u16 As[128*32];
    __shared__ __align__(16) u16 Bs[128*32];
    const int b  = blockIdx.z;
    const int n0 = blockIdx.x * 128;   // cout
    const int m0 = blockIdx.y * 128;   // pixel
    const int t  = threadIdx.x;
    const int lane = t & 63;
    const int w    = __builtin_amdgcn_readfirstlane(t >> 6);
    const int wm   = (w >> 1) * 64;
    const int wn   = (w & 1) * 64;
    const int l15  = lane & 15;
    const int hi   = lane >> 4;
    const int srow = lane >> 2;
    const int scol = (lane & 3) << 3;

    f32x4 acc1[4][4], acc2[4][4];
    #pragma unroll
    for (int i = 0; i < 4; ++i)
        #pragma unroll
        for (int j = 0; j < 4; ++j) {
            acc1[i][j][0]=0.f; acc1[i][j][1]=0.f; acc1[i][j][2]=0.f; acc1[i][j][3]=0.f;
            acc2[i][j][0]=0.f; acc2[i][j][1]=0.f; acc2[i][j][2]=0.f; acc2[i][j][3]=0.f;
        }

    const u16* Ab = SAT  + (ll)b * HW * 192;
    const u16* Bb = WGHT + (ll)b * 512 * 192;
    const int ar0 = min(m0 + 32*w + srow,      HW-1);
    const int ar1 = min(m0 + 32*w + 16 + srow, HW-1);
    const int br0 = n0 + 32*w + srow;
    const int br1 = br0 + 16;
    u16* A0 = As + (32*w)*32;  u16* A1 = A0 + 16*32;
    u16* B0 = Bs + (32*w)*32;  u16* B1 = B0 + 16*32;

    #pragma unroll
    for (int kc = 0; kc < 6; ++kc) {
        const int k0 = kc << 5;
        __syncthreads();
        glds16(Ab + (ll)ar0 * 192 + k0 + scol, A0);
        glds16(Ab + (ll)ar1 * 192 + k0 + scol, A1);
        glds16(Bb + (ll)br0 * 192 + k0 + scol, B0);
        glds16(Bb + (ll)br1 * 192 + k0 + scol, B1);
        __syncthreads();
        s16x8 af[4], bfr[4];
        #pragma unroll
        for (int i = 0; i < 4; ++i) {
            af[i]  = *(const s16x8*)(As + (wm + i*16 + l15)*32 + hi*8);
            bfr[i] = *(const s16x8*)(Bs + (wn + i*16 + l15)*32 + hi*8);
        }
        if (kc < 2) {
            #pragma unroll
            for (int i = 0; i < 4; ++i)
                #pragma unroll
                for (int j = 0; j < 4; ++j)
                    acc1[i][j] = __builtin_amdgcn_mfma_f32_16x16x32_bf16(af[i], bfr[j], acc1[i][j], 0, 0, 0);
        } else {
            #pragma unroll
            for (int i = 0; i < 4; ++i)
                #pragma unroll
                for (int j = 0; j < 4; ++j)
                    acc2[i][j] = __builtin_amdgcn_mfma_f32_16x16x32_bf16(af[i], bfr[j], acc2[i][j], 0, 0, 0);
        }
    }

    u16* Ud = Upad + (ll)b * UROWS * CIN;
    #pragma unroll
    for (int i = 0; i < 4; ++i) {
        #pragma unroll
        for (int j = 0; j < 4; ++j) {
            const int n = n0 + wn + j*16 + l15;      // cout < 512 always
            #pragma unroll
            for (int r = 0; r < 4; ++r) {
                const int m = m0 + wm + i*16 + hi*4 + r;   // pixel
                if (m >= HW) continue;
                float v1 = fmaxf((acc1[i][j][r] + bE[n]) * scale[n] + shift[n], 0.f);
                float v2 = fmaxf((acc2[i][j][r] + bE[n]) * scale[n] + shift[n], 0.f);
                float xv = b2f(xT[((ll)0 + (ll)blockIdx.z*HW + m)*CIN + n]);
                const int y = m / 56, xx = m % 56;
                const ll  u = GUARD + (ll)(y + 1) * PADW + (xx + 1);
                Ud[u*CIN + n] = f2b(v1 + v2 + xv);
            }
        }
    }
}

// ---------------------------------------------------------------------------
// conv3x3: per kc stage a 256-row B window once (XOR-swizzled via pre-swizzled
// glds16 source + swizzled ds_read); A-frags from L2 (frag-ordered Ws9f) into
// registers, double-buffered per tap. One barrier per kc, 144 MFMA between.
// XCD-swizzled 1-D grid of 864 blocks.
// ---------------------------------------------------------------------------
#define STAGEB(BUF, KC) { \
    const int k0s = (KC) << 5; \
    _Pragma("unroll") \
    for (int c = 0; c < 4; ++c) { \
        const int R0 = (w << 6) + (c << 4); \
        const int rd = R0 + lrow; \
        const int hd = lq ^ ((rd >> 1) & 3); \
        const int ur = min(n0 + rd, UROWS - 1); \
        glds16(Ub + (ll)ur * CIN + k0s + hd * 8, &Bwin[BUF][R0 * 32]); \
    } }

#define TAP(S, AFU, AFP) { \
    constexpr int doff = ((S)/3 - 1) * PADW + ((S)%3 - 1); \
    if ((S) < 8) { \
        const u16* an = WF + (ll)((mt*9 + (S)+1)*16 + kc) * 4096; \
        _Pragma("unroll") \
        for (int i = 0; i < 4; ++i) \
            AFP[i] = *(const s16x8*)(an + ((mbase + i)*64 + lane)*8); \
    } \
    s16x8 bfr[4]; \
    _Pragma("unroll") \
    for (int j = 0; j < 4; ++j) { \
        const int wr = wn + j*16 + l15 + doff + 64; \
        const int g  = (wr << 2) + (hi ^ ((wr >> 1) & 3)); \
        bfr[j] = *(const s16x8*)(&Bwin[cur][g << 3]); \
    } \
    _Pragma("unroll") \
    for (int i = 0; i < 4; ++i) \
        _Pragma("unroll") \
        for (int j = 0; j < 4; ++j) \
            acc[i][j] = __builtin_amdgcn_mfma_f32_16x16x32_bf16(AFU[i], bfr[j], acc[i][j], 0, 0, 0); \
}

__global__ __launch_bounds__(256) void conv9_kernel(
    const u16* __restrict__ WF, const u16* __restrict__ UpadT,
    const float* __restrict__ bout, float* __restrict__ out)
{
    __shared__ __align__(16) u16 Bwin[2][256*32];
    const int id  = blockIdx.x;                 // 0..863
    const int lid = (id & 7) * 108 + (id >> 3); // contiguous chunk per XCD
    const int mt  = lid / 216;
    const int r1  = lid % 216;
    const int b   = r1 / 27;
    const int nt  = r1 % 27;
    const int m0 = mt << 7, n0 = nt << 7;

    const int t = threadIdx.x;
    const int lane = t & 63;
    const int w    = __builtin_amdgcn_readfirstlane(t >> 6);
    const int wm   = (w >> 1) * 64;
    const int wn   = (w & 1) * 64;
    const int l15  = lane & 15;
    const int hi   = lane >> 4;     // 0..3
    const int lrow = lane >> 2;     // staging row within 16-block
    const int lq   = lane & 3;      // staging granule slot
    const int mbase = wm >> 4;

    f32x4 acc[4][4];
    #pragma unroll
    for (int i = 0; i < 4; ++i)
        #pragma unroll
        for (int j = 0; j < 4; ++j) { acc[i][j][0]=0.f; acc[i][j][1]=0.f; acc[i][j][2]=0.f; acc[i][j][3]=0.f; }

    const u16* Ub = UpadT + (ll)b * UROWS * CIN;

    STAGEB(0, 0);
    __syncthreads();

    for (int kc = 0; kc < 16; ++kc) {
        const int cur = kc & 1;
        if (kc < 15) STAGEB(cur ^ 1, kc + 1);
        s16x8 afA[4], afB[4];
        {
            const u16* a0 = WF + (ll)((mt*9 + 0)*16 + kc) * 4096;
            #pragma unroll
            for (int i = 0; i < 4; ++i)
                afA[i] = *(const s16x8*)(a0 + ((mbase + i)*64 + lane)*8);
        }
        TAP(0, afA, afB) TAP(1, afB, afA) TAP(2, afA, afB)
        TAP(3, afB, afA) TAP(4, afA, afB) TAP(5, afB, afA)
        TAP(6, afA, afB) TAP(7, afB, afA) TAP(8, afA, afB)
        __syncthreads();
    }

    #pragma unroll
    for (int i = 0; i < 4; ++i) {
        #pragma unroll
        for (int j = 0; j < 4; ++j) {
            const int pc = n0 + wn + j*16 + l15;
            const int y = pc / PADW, xx = pc % PADW;
            if (y >= 1 && y <= 56 && xx >= 1 && xx <= 56) {
                const int p = (y - 1) * 56 + (xx - 1);
                #pragma unroll
                for (int r = 0; r < 4; ++r) {
                    const int m = m0 + wm + i*16 + hi*4 + r;
                    out[((ll)b * CIN + m) * HW + p] = acc[i][j][r] + bout[m];
                }
            }
        }
    }
}

// ---------------------------------------------------------------------------
extern "C" void kernel_launch(void* const* d_in, const int* in_sizes, int n_in,
                              void* d_out, int out_size, void* d_ws, size_t ws_size,
                              hipStream_t stream)
{
    const float* x    = (const float*)d_in[0];
    const float* WA   = (const float*)d_in[1];
    const float* bA   = (const float*)d_in[2];
    const float* WB   = (const float*)d_in[3];
    const float* bB   = (const float*)d_in[4];
    const float* WV   = (const float*)d_in[5];
    const float* bV   = (const float*)d_in[6];
    const float* WAs  = (const float*)d_in[7];
    const float* bAs  = (const float*)d_in[8];
    const float* WBs  = (const float*)d_in[9];
    const float* bBs  = (const float*)d_in[10];
    const float* WVs  = (const float*)d_in[11];
    const float* bVs  = (const float*)d_in[12];
    const float* WE   = (const float*)d_in[13];
    const float* bE   = (const float*)d_in[14];
    const float* bng  = (const float*)d_in[15];
    const float* bnb  = (const float*)d_in[16];
    const float* bnm  = (const float*)d_in[17];
    const float* bnv  = (const float*)d_in[18];
    const float* Wout = (const float*)d_in[19];
    const float* bout = (const float*)d_in[20];
    float* out = (float*)d_out;

    char* ws = (char*)d_ws;
    u16*   xT    = (u16*)  (ws + OFF_XT);
    u16*   P     = (u16*)  (ws + OFF_P);
    u16*   SAT   = (u16*)  (ws + OFF_SAT);
    u16*   GHT   = (u16*)  (ws + OFF_GHT);
    u16*   WGHT  = (u16*)  (ws + OFF_ZT);
    float* partG = (float*)(ws + OFF_ZT);    // consumed by reduce_gh before WGHT written
    float* partH = (float*)(ws + OFF_ZST);
    u16*   Upad  = (u16*)  (ws + OFF_UPAD);
    u16*   Wcat  = (u16*)  (ws + OFF_WCAT);
    float* bcat  = (float*)(ws + OFF_BCAT);
    u16*   WEb   = (u16*)  (ws + OFF_WEB);
    u16*   Ws9f  = (u16*)  (ws + OFF_WS9);
    float* scale = (float*)(ws + OFF_SCALE);
    float* shift = (float*)(ws + OFF_SHIFT);

    // 1. weight packing / bn fold / conv-weight frag permutation
    prep_kernel<<<2048, 256, 0, stream>>>(WA, WB, WV, WAs, WBs, WVs,
                                          bA, bB, bV, bAs, bBs, bVs,
                                          WE, bng, bnb, bnm, bnv, Wout,
                                          Wcat, bcat, WEb, Ws9f, scale, shift);

    // 2. xT[p][c] = bf16(x[c][p])
    transpose_kernel<float><<<dim3(98, 16, 8), 256, 0, stream>>>(
        x, xT, CIN, HW, (ll)CIN * HW, (ll)HW * CIN, CIN, 0);

    // 3. fused projection: P[o][p]
    gemm_bt_kernel<0><<<dim3(25, 5, 8), 256, 0, stream>>>(
        Wcat, CIN, 0, xT, CIN, (ll)HW * CIN, P, HW, (ll)MPROJ * HW,
        MPROJ, HW, CIN, bcat);

    // 4. spatial softmax for B rows
    softmax_rows_kernel<<<dim3(64, 8), 256, 0, stream>>>(P);

    // 5. channel softmax for V / B_S / V_S
    softmax_cols_kernel<<<dim3(98, 3), 256, 0, stream>>>(P);

    // 6. transposes into SAT: cols 0..63 = softV^T, cols 64..191 = A_S^T
    transpose_kernel<u16><<<dim3(98, 2, 8), 256, 0, stream>>>(
        P + (ll)192 * HW, SAT, CN, HW, (ll)MPROJ * HW, (ll)HW * 192, 192, 0);
    transpose_kernel<u16><<<dim3(98, 4, 8), 256, 0, stream>>>(
        P + (ll)256 * HW, SAT, CM, HW, (ll)MPROJ * HW, (ll)HW * 192, 192, 64);

    // 7. G/H split-K partials + reduce into GHT (transposed)
    gemm_gh_kernel<<<112, 256, 0, stream>>>(P, partG, partH);
    reduce_gh_kernel<<<768, 256, 0, stream>>>(partG, partH, GHT);

    // 8. WGHT[cout][0..63]=W1T, [64..191]=W2T : A=WEb[512][128], Bt=GHT[192][128]
    gemm_bt_kernel<1><<<dim3(2, 4, 8), 256, 0, stream>>>(
        WEb, CM, 0, GHT, CM, (ll)192 * CM, WGHT, 192, (ll)512 * 192,
        512, 192, CM, nullptr);

    // 9. zero padded residual buffer (borders + guards)
    hipMemsetAsync(Upad, 0, (size_t)BATCH * UROWS * CIN * sizeof(u16), stream);

    // 10. fused E1+E2+residual into Upad interior
    e12_kernel<<<dim3(4, 25, 8), 256, 0, stream>>>(
        SAT, WGHT, xT, bE, scale, shift, Upad);

    // 11. 3x3 conv: window-staged shift-GEMMs
    conv9_kernel<<<864, 256, 0, stream>>>(Ws9f, Upad, bout, out);

    (void)in_sizes; (void)n_in; (void)out_size; (void)ws_size;
}

// Round 8
// 474.788 us; speedup vs baseline: 1.7745x; 1.1284x over previous
//
#include <hip/hip_runtime.h>

typedef short s16x8 __attribute__((ext_vector_type(8)));
typedef float f32x4 __attribute__((ext_vector_type(4)));
using u16 = unsigned short;
using ll = long long;

// ---------- bf16 helpers (bit-level, RNE) ----------
__device__ inline u16 f2b(float f) {
    union { float f; unsigned int i; } u; u.f = f;
    unsigned int r = u.i + 0x7FFFu + ((u.i >> 16) & 1u);
    return (u16)(r >> 16);
}
__device__ inline float b2f(u16 v) {
    union { unsigned int i; float f; } u; u.i = ((unsigned int)v) << 16; return u.f;
}

// global -> LDS async copy, 16B per lane. LDS dest wave-uniform base; lane l
// lands at base + l*16 bytes. [guide §5, m97/m104]
__device__ __forceinline__ void glds16(const u16* g, u16* lds) {
    __builtin_amdgcn_global_load_lds(
        (const __attribute__((address_space(1))) void*)g,
        (__attribute__((address_space(3))) void*)lds,
        16, 0, 0);
}

// ---------- problem constants ----------
#define BATCH 8
#define CIN   512
#define HW    3136   // 56*56
#define CM    128
#define CN    64
#define MPROJ 640
#define PADW  58
#define PADHW 3364   // 58*58
#define GUARD 64
#define UROWS (PADHW + 2*GUARD)  // 3492
#define GH_KS 7      // split-K for G/H (3136 = 7*448)

// ws offsets (bytes)
#define OFF_XT     0LL                                 // [8][3136][512] bf16
#define OFF_P      25690112LL                          // [8][640][3136] bf16
#define OFF_SAT    57802752LL                          // [8][3136][192] bf16 (9.63MB)
#define OFF_GHT    67436544LL                          // [8][192][128]  bf16 (393KB)
#define OFF_ZT     67829760LL                          // partG f32 / then WGHT [8][512][192] bf16
#define OFF_ZST    74252288LL                          // partH f32 (transient)
#define OFF_UPAD   80674816LL                          // [8][3492][512] bf16
#define OFF_WCAT   109281280LL                         // [640][512] bf16
#define OFF_BCAT   109936640LL                         // [640] f32
#define OFF_WEB    109939200LL                         // [512][128] bf16
#define OFF_WS9    110070272LL                         // Ws9f frag-ordered [4][9][16][8][64][8] bf16
#define OFF_SCALE  114788864LL
#define OFF_SHIFT  114790912LL

// ---------------------------------------------------------------------------
// prep: pack weights to bf16, fold bn. Ws9f: Wout permuted into MFMA A-frag
// order [mt][s][kc][mb][lane64][8e] so conv9 A-loads are 1KB coalesced.
// ---------------------------------------------------------------------------
__global__ void prep_kernel(
    const float* __restrict__ WA,  const float* __restrict__ WB,  const float* __restrict__ WV,
    const float* __restrict__ WAs, const float* __restrict__ WBs, const float* __restrict__ WVs,
    const float* __restrict__ bA,  const float* __restrict__ bB,  const float* __restrict__ bV,
    const float* __restrict__ bAs, const float* __restrict__ bBs, const float* __restrict__ bVs,
    const float* __restrict__ WE,  const float* __restrict__ bng, const float* __restrict__ bnb,
    const float* __restrict__ bnm, const float* __restrict__ bnv, const float* __restrict__ Wout,
    u16* __restrict__ Wcat, float* __restrict__ bcat, u16* __restrict__ WEb,
    u16* __restrict__ Ws9f, float* __restrict__ scale, float* __restrict__ shift)
{
    ll tid = (ll)blockIdx.x * blockDim.x + threadIdx.x;
    ll stride = (ll)gridDim.x * blockDim.x;
    // Wcat rows: A 0..127 | B 128..191 | V 192..255 | A_S 256..383 | B_S 384..511 | V_S 512..639
    for (ll i = tid; i < (ll)MPROJ * CIN; i += stride) {
        int o = (int)(i / CIN), c = (int)(i % CIN);
        float v;
        if      (o < 128) v = WA [(o      )*CIN + c];
        else if (o < 192) v = WB [(o - 128)*CIN + c];
        else if (o < 256) v = WV [(o - 192)*CIN + c];
        else if (o < 384) v = WAs[(o - 256)*CIN + c];
        else if (o < 512) v = WBs[(o - 384)*CIN + c];
        else              v = WVs[(o - 512)*CIN + c];
        Wcat[i] = f2b(v);
    }
    for (ll i = tid; i < MPROJ; i += stride) {
        int o = (int)i; float v;
        if      (o < 128) v = bA [o];
        else if (o < 192) v = bB [o - 128];
        else if (o < 256) v = bV [o - 192];
        else if (o < 384) v = bAs[o - 256];
        else if (o < 512) v = bBs[o - 384];
        else              v = bVs[o - 512];
        bcat[i] = v;
    }
    for (ll i = tid; i < (ll)CIN * CM; i += stride) WEb[i] = f2b(WE[i]);
    // Ws9f[mt][s][kc][mb][lane][e]: lane = hic*16 + (o&15); covers (row o, chans kc*32+hic*8+e)
    for (ll oc = tid; oc < (ll)CIN * CIN; oc += stride) {
        int o = (int)(oc >> 9), c = (int)(oc & 511);
        int mt = o >> 7, mb = (o >> 4) & 7, lo = o & 15;
        int kc = c >> 5, hic = (c >> 3) & 3, e = c & 7;
        #pragma unroll
        for (int s = 0; s < 9; ++s) {
            ll idx = ((((ll)(mt*9 + s)*16 + kc)*8 + mb)*64 + hic*16 + lo)*8 + e;
            Ws9f[idx] = f2b(Wout[oc * 9 + s]);
        }
    }
    for (ll i = tid; i < CIN; i += stride) {
        float sc = bng[i] * rsqrtf(bnv[i] + 1e-5f);
        scale[i] = sc;
        shift[i] = bnb[i] - bnm[i] * sc;
    }
}

// ---------------------------------------------------------------------------
// transpose [R][C] -> dst[c][ldD..]: dst[c*ldD + dcol + r]. R,C mult of 32.
// ---------------------------------------------------------------------------
template<typename T>
__global__ __launch_bounds__(256) void transpose_kernel(
    const T* __restrict__ src, u16* __restrict__ dst,
    int R, int C, ll sS, ll sD, int ldD, int dcol)
{
    __shared__ u16 tile[32][33];
    int b  = blockIdx.z;
    int c0 = blockIdx.x << 5, r0 = blockIdx.y << 5;
    int tc = threadIdx.x & 31, tr = threadIdx.x >> 5;
    const T* s = src + sS * b;
    #pragma unroll
    for (int i = 0; i < 4; ++i) {
        int r = tr + i * 8;
        T v = s[(ll)(r0 + r) * C + c0 + tc];
        u16 u;
        if constexpr (sizeof(T) == 4) u = f2b((float)v);
        else                          u = (u16)v;
        tile[r][tc] = u;
    }
    __syncthreads();
    u16* d = dst + sD * b;
    #pragma unroll
    for (int i = 0; i < 4; ++i) {
        int c = tr + i * 8;
        d[(ll)(c0 + c) * ldD + dcol + r0 + tc] = tile[tc][c];
    }
}

// ---------------------------------------------------------------------------
// generic bf16 MFMA GEMM:  C[m,n] = sum_k A[m,k] * Bt[n,k]
// EPI: 0 = +rowBias -> bf16 C   1 = plain -> bf16 C
// ---------------------------------------------------------------------------
template<int EPI>
__global__ __launch_bounds__(256) void gemm_bt_kernel(
    const u16* __restrict__ A, ll ldA, ll sA,
    const u16* __restrict__ Bt, ll ldB, ll sB,
    u16* __restrict__ C, ll ldC, ll sC,
    int M, int N, int K,
    const float* __restrict__ rowBias)
{
    __shared__ __align__(16) u16 As[128*32];
    __shared__ __align__(16) u16 Bs[128*32];
    const int b  = blockIdx.z;
    const int n0 = blockIdx.x * 128;
    const int m0 = blockIdx.y * 128;
    const int t  = threadIdx.x;
    const int lane = t & 63;
    const int w    = __builtin_amdgcn_readfirstlane(t >> 6);
    const int wm   = (w >> 1) * 64;
    const int wn   = (w & 1) * 64;
    const int l15  = lane & 15;
    const int hi   = lane >> 4;
    const int srow = lane >> 2;
    const int scol = (lane & 3) << 3;

    f32x4 acc[4][4];
    #pragma unroll
    for (int i = 0; i < 4; ++i)
        #pragma unroll
        for (int j = 0; j < 4; ++j) { acc[i][j][0]=0.f; acc[i][j][1]=0.f; acc[i][j][2]=0.f; acc[i][j][3]=0.f; }

    const u16* Ab = A  + sA * b;
    const u16* Bb = Bt + sB * b;
    const int nk = K >> 5;

    const int ar0 = min(m0 + 32*w + srow,      M-1);
    const int ar1 = min(m0 + 32*w + 16 + srow, M-1);
    const int br0 = min(n0 + 32*w + srow,      N-1);
    const int br1 = min(n0 + 32*w + 16 + srow, N-1);
    u16* A0 = As + (32*w)*32;  u16* A1 = A0 + 16*32;
    u16* B0 = Bs + (32*w)*32;  u16* B1 = B0 + 16*32;

    for (int kc = 0; kc < nk; ++kc) {
        const int k0 = kc << 5;
        __syncthreads();
        glds16(Ab + (ll)ar0 * ldA + k0 + scol, A0);
        glds16(Ab + (ll)ar1 * ldA + k0 + scol, A1);
        glds16(Bb + (ll)br0 * ldB + k0 + scol, B0);
        glds16(Bb + (ll)br1 * ldB + k0 + scol, B1);
        __syncthreads();
        s16x8 af[4], bfr[4];
        #pragma unroll
        for (int i = 0; i < 4; ++i) {
            af[i]  = *(const s16x8*)(As + (wm + i*16 + l15)*32 + hi*8);
            bfr[i] = *(const s16x8*)(Bs + (wn + i*16 + l15)*32 + hi*8);
        }
        #pragma unroll
        for (int i = 0; i < 4; ++i)
            #pragma unroll
            for (int j = 0; j < 4; ++j)
                acc[i][j] = __builtin_amdgcn_mfma_f32_16x16x32_bf16(af[i], bfr[j], acc[i][j], 0, 0, 0);
    }

    #pragma unroll
    for (int i = 0; i < 4; ++i) {
        #pragma unroll
        for (int j = 0; j < 4; ++j) {
            const int n = n0 + wn + j*16 + l15;
            if (n >= N) continue;
            #pragma unroll
            for (int r = 0; r < 4; ++r) {
                const int m = m0 + wm + i*16 + hi*4 + r;
                if (m >= M) continue;
                float v = acc[i][j][r];
                if constexpr (EPI == 0) v += rowBias[m];
                C[sC*b + (ll)m*ldC + n] = f2b(v);
            }
        }
    }
}

// ---------------------------------------------------------------------------
// split-K GEMM for G (128x64 K=3136) and H (128x128 K=3136) partials
// ---------------------------------------------------------------------------
__global__ __launch_bounds__(256) void gemm_gh_kernel(
    const u16* __restrict__ P, float* __restrict__ partG, float* __restrict__ partH)
{
    __shared__ __align__(16) u16 As[128*32];
    __shared__ __align__(16) u16 Bs[128*32];
    const int z   = blockIdx.x;
    const bool isH = (z >= 56);
    const int zz  = isH ? z - 56 : z;
    const int b   = zz / GH_KS, ks = zz % GH_KS;
    const int N   = isH ? 128 : 64;
    const u16* Ab = P + (ll)b*MPROJ*HW + (isH ? (ll)512*HW : 0LL);
    const u16* Bb = P + (ll)b*MPROJ*HW + (isH ? (ll)384*HW : (ll)128*HW);
    float* Cp = isH ? (partH + (ll)zz*CM*CM) : (partG + (ll)zz*CM*CN);

    const int t = threadIdx.x;
    const int lane = t & 63;
    const int w    = __builtin_amdgcn_readfirstlane(t >> 6);
    const int wm   = (w >> 1) * 64;
    const int wn   = (w & 1) * 64;
    const int l15  = lane & 15;
    const int hi   = lane >> 4;
    const int srow = lane >> 2;
    const int scol = (lane & 3) << 3;

    f32x4 acc[4][4];
    #pragma unroll
    for (int i = 0; i < 4; ++i)
        #pragma unroll
        for (int j = 0; j < 4; ++j) { acc[i][j][0]=0.f; acc[i][j][1]=0.f; acc[i][j][2]=0.f; acc[i][j][3]=0.f; }

    const int ar0 = 32*w + srow;
    const int ar1 = ar0 + 16;
    const int br0 = min(32*w + srow,      N-1);
    const int br1 = min(32*w + 16 + srow, N-1);
    u16* A0 = As + (32*w)*32;  u16* A1 = A0 + 16*32;
    u16* B0 = Bs + (32*w)*32;  u16* B1 = B0 + 16*32;
    const int k0base = ks * (HW / GH_KS);

    for (int kc = 0; kc < 14; ++kc) {
        const int k0 = k0base + (kc << 5);
        __syncthreads();
        glds16(Ab + (ll)ar0 * HW + k0 + scol, A0);
        glds16(Ab + (ll)ar1 * HW + k0 + scol, A1);
        glds16(Bb + (ll)br0 * HW + k0 + scol, B0);
        glds16(Bb + (ll)br1 * HW + k0 + scol, B1);
        __syncthreads();
        s16x8 af[4], bfr[4];
        #pragma unroll
        for (int i = 0; i < 4; ++i) {
            af[i]  = *(const s16x8*)(As + (wm + i*16 + l15)*32 + hi*8);
            bfr[i] = *(const s16x8*)(Bs + (wn + i*16 + l15)*32 + hi*8);
        }
        #pragma unroll
        for (int i = 0; i < 4; ++i)
            #pragma unroll
            for (int j = 0; j < 4; ++j)
                acc[i][j] = __builtin_amdgcn_mfma_f32_16x16x32_bf16(af[i], bfr[j], acc[i][j], 0, 0, 0);
    }

    #pragma unroll
    for (int i = 0; i < 4; ++i) {
        #pragma unroll
        for (int j = 0; j < 4; ++j) {
            const int n = wn + j*16 + l15;
            if (n >= N) continue;
            #pragma unroll
            for (int r = 0; r < 4; ++r) {
                const int m = wm + i*16 + hi*4 + r;
                Cp[(ll)m * N + n] = acc[i][j][r];
            }
        }
    }
}

// reduce partials -> GHT[b][192][128]: rows 0..63 = G^T, rows 64..191 = H^T
__global__ void reduce_gh_kernel(const float* __restrict__ pg, const float* __restrict__ ph,
                                 u16* __restrict__ GHT)
{
    int i = blockIdx.x * 256 + threadIdx.x;
    if (i < BATCH*CM*CN) {
        int b = i / (CM*CN), r = i % (CM*CN);
        int m = r / CN, n = r % CN;
        float s = 0.f;
        #pragma unroll
        for (int ks = 0; ks < GH_KS; ++ks) s += pg[(ll)(b*GH_KS+ks)*CM*CN + r];
        GHT[(ll)b*192*128 + (ll)n*128 + m] = f2b(s);
    } else {
        int j = i - BATCH*CM*CN;
        if (j < BATCH*CM*CM) {
            int b = j / (CM*CM), r = j % (CM*CM);
            int m = r / CM, mp = r % CM;
            float s = 0.f;
            #pragma unroll
            for (int ks = 0; ks < GH_KS; ++ks) s += ph[(ll)(b*GH_KS+ks)*CM*CM + r];
            GHT[(ll)b*192*128 + (ll)(64+mp)*128 + m] = f2b(s);
        }
    }
}

// ---------------------------------------------------------------------------
// softmax over spatial (3136) for the 64 B-rows of P, in place
// ---------------------------------------------------------------------------
__global__ __launch_bounds__(256) void softmax_rows_kernel(u16* __restrict__ P)
{
    __shared__ float red[4];
    __shared__ float red2[4];
    const int b = blockIdx.y, row = 128 + blockIdx.x;
    u16* p = P + ((ll)b * MPROJ + row) * HW;
    const int t = threadIdx.x;
    float vals[13];
    int cnt = 0;
    float m = -1e30f;
    for (int j = t; j < HW; j += 256) { float v = b2f(p[j]); vals[cnt++] = v; m = fmaxf(m, v); }
    #pragma unroll
    for (int o = 32; o; o >>= 1) m = fmaxf(m, __shfl_xor(m, o));
    const int wid = t >> 6;
    if ((t & 63) == 0) red[wid] = m;
    __syncthreads();
    m = fmaxf(fmaxf(red[0], red[1]), fmaxf(red[2], red[3]));
    float s = 0.f;
    for (int i = 0; i < cnt; ++i) { vals[i] = __expf(vals[i] - m); s += vals[i]; }
    #pragma unroll
    for (int o = 32; o; o >>= 1) s += __shfl_xor(s, o);
    if ((t & 63) == 0) red2[wid] = s;
    __syncthreads();
    s = red2[0] + red2[1] + red2[2] + red2[3];
    const float inv = 1.f / s;
    cnt = 0;
    for (int j = t; j < HW; j += 256) p[j] = f2b(vals[cnt++] * inv);
}

// ---------------------------------------------------------------------------
// channel softmax per pixel in place: 0=V(192,64) 1=B_S(384,128) 2=V_S(512,128)
// ---------------------------------------------------------------------------
__global__ void softmax_cols_kernel(u16* __restrict__ P)
{
    int idx = blockIdx.x * 256 + threadIdx.x;
    if (idx >= BATCH * HW) return;
    const int b = idx / HW, p = idx % HW;
    int off, n;
    if      (blockIdx.y == 0) { off = 192; n = 64;  }
    else if (blockIdx.y == 1) { off = 384; n = 128; }
    else                      { off = 512; n = 128; }
    u16* g = P + (ll)b * MPROJ * HW + (ll)off * HW + p;
    float m = -1e30f, s = 0.f;
    for (int i = 0; i < n; ++i) {
        float v  = b2f(g[(ll)i * HW]);
        float nm = fmaxf(m, v);
        s = s * __expf(m - nm) + __expf(v - nm);
        m = nm;
    }
    const float inv = 1.f / s;
    for (int i = 0; i < n; ++i) {
        const ll o = (ll)i * HW;
        g[o] = f2b(__expf(b2f(g[o]) - m) * inv);
    }
}

// ---------------------------------------------------------------------------
// e12: C[p][cout] dual-accumulator GEMM over SAT[3136][192] x WGHT[512][192]:
// kc 0..1 -> acc1 (E1pre), kc 2..5 -> acc2 (E2pre); epilogue applies
// relu(bn(.+bE)) to each, sums, adds x residual, writes Upad interior once.
// ---------------------------------------------------------------------------
__global__ __launch_bounds__(256) void e12_kernel(
    const u16* __restrict__ SAT, const u16* __restrict__ WGHT,
    const u16* __restrict__ xT,  const float* __restrict__ bE,
    const float* __restrict__ scale, const float* __restrict__ shift,
    u16* __restrict__ Upad)
{
    __shared__ __align__(16) u16 As[128*32];
    __shared__ __align__(16) u16 Bs[128*32];
    const int b  = blockIdx.z;
    const int n0 = blockIdx.x * 128;   // cout
    const int m0 = blockIdx.y * 128;   // pixel
    const int t  = threadIdx.x;
    const int lane = t & 63;
    const int w    = __builtin_amdgcn_readfirstlane(t >> 6);
    const int wm   = (w >> 1) * 64;
    const int wn   = (w & 1) * 64;
    const int l15  = lane & 15;
    const int hi   = lane >> 4;
    const int srow = lane >> 2;
    const int scol = (lane & 3) << 3;

    f32x4 acc1[4][4], acc2[4][4];
    #pragma unroll
    for (int i = 0; i < 4; ++i)
        #pragma unroll
        for (int j = 0; j < 4; ++j) {
            acc1[i][j][0]=0.f; acc1[i][j][1]=0.f; acc1[i][j][2]=0.f; acc1[i][j][3]=0.f;
            acc2[i][j][0]=0.f; acc2[i][j][1]=0.f; acc2[i][j][2]=0.f; acc2[i][j][3]=0.f;
        }

    const u16* Ab = SAT  + (ll)b * HW * 192;
    const u16* Bb = WGHT + (ll)b * 512 * 192;
    const int ar0 = min(m0 + 32*w + srow,      HW-1);
    const int ar1 = min(m0 + 32*w + 16 + srow, HW-1);
    const int br0 = n0 + 32*w + srow;
    const int br1 = br0 + 16;
    u16* A0 = As + (32*w)*32;  u16* A1 = A0 + 16*32;
    u16* B0 = Bs + (32*w)*32;  u16* B1 = B0 + 16*32;

    #pragma unroll
    for (int kc = 0; kc < 6; ++kc) {
        const int k0 = kc << 5;
        __syncthreads();
        glds16(Ab + (ll)ar0 * 192 + k0 + scol, A0);
        glds16(Ab + (ll)ar1 * 192 + k0 + scol, A1);
        glds16(Bb + (ll)br0 * 192 + k0 + scol, B0);
        glds16(Bb + (ll)br1 * 192 + k0 + scol, B1);
        __syncthreads();
        s16x8 af[4], bfr[4];
        #pragma unroll
        for (int i = 0; i < 4; ++i) {
            af[i]  = *(const s16x8*)(As + (wm + i*16 + l15)*32 + hi*8);
            bfr[i] = *(const s16x8*)(Bs + (wn + i*16 + l15)*32 + hi*8);
        }
        if (kc < 2) {
            #pragma unroll
            for (int i = 0; i < 4; ++i)
                #pragma unroll
                for (int j = 0; j < 4; ++j)
                    acc1[i][j] = __builtin_amdgcn_mfma_f32_16x16x32_bf16(af[i], bfr[j], acc1[i][j], 0, 0, 0);
        } else {
            #pragma unroll
            for (int i = 0; i < 4; ++i)
                #pragma unroll
                for (int j = 0; j < 4; ++j)
                    acc2[i][j] = __builtin_amdgcn_mfma_f32_16x16x32_bf16(af[i], bfr[j], acc2[i][j], 0, 0, 0);
        }
    }

    u16* Ud = Upad + (ll)b * UROWS * CIN;
    #pragma unroll
    for (int i = 0; i < 4; ++i) {
        #pragma unroll
        for (int j = 0; j < 4; ++j) {
            const int n = n0 + wn + j*16 + l15;      // cout < 512 always
            #pragma unroll
            for (int r = 0; r < 4; ++r) {
                const int m = m0 + wm + i*16 + hi*4 + r;   // pixel
                if (m >= HW) continue;
                float v1 = fmaxf((acc1[i][j][r] + bE[n]) * scale[n] + shift[n], 0.f);
                float v2 = fmaxf((acc2[i][j][r] + bE[n]) * scale[n] + shift[n], 0.f);
                float xv = b2f(xT[((ll)blockIdx.z*HW + m)*CIN + n]);
                const int y = m / 56, xx = m % 56;
                const ll  u = GUARD + (ll)(y + 1) * PADW + (xx + 1);
                Ud[u*CIN + n] = f2b(v1 + v2 + xv);
            }
        }
    }
}

// ---------------------------------------------------------------------------
// conv3x3: per kc stage a 256-row B window once (XOR-swizzled via pre-swizzled
// glds16 source + swizzled ds_read); A-frags from L2 (frag-ordered Ws9f) into
// registers with 3-buffer rotation. ISSUE ORDER per kc: A(tap0),A(tap1) regs
// FIRST, then the window glds16 — keeps the slow window loads NEWEST in the
// vmcnt queue so per-tap A-waits are counted (no vmcnt(0) drain of the HBM/L3
// prefetch; vmcnt retires strictly in issue order). setprio(1) around MFMA.
// ---------------------------------------------------------------------------
#define STAGEB(BUF, KC) { \
    const int k0s = (KC) << 5; \
    _Pragma("unroll") \
    for (int c = 0; c < 4; ++c) { \
        const int R0 = (w << 6) + (c << 4); \
        const int rd = R0 + lrow; \
        const int hd = lq ^ ((rd >> 1) & 3); \
        const int ur = min(n0 + rd, UROWS - 1); \
        glds16(Ub + (ll)ur * CIN + k0s + hd * 8, &Bwin[BUF][R0 * 32]); \
    } }

#define TAP2(S, USE, PF) { \
    constexpr int doff = ((S)/3 - 1) * PADW + ((S)%3 - 1); \
    if ((S) < 7) { \
        const u16* an = WF + (ll)((mt*9 + (S)+2)*16 + kc) * 4096; \
        _Pragma("unroll") \
        for (int i = 0; i < 4; ++i) \
            PF[i] = *(const s16x8*)(an + ((mbase + i)*64 + lane)*8); \
    } \
    s16x8 bfr[4]; \
    _Pragma("unroll") \
    for (int j = 0; j < 4; ++j) { \
        const int wr = wn + j*16 + l15 + doff + 64; \
        const int g  = (wr << 2) + (hi ^ ((wr >> 1) & 3)); \
        bfr[j] = *(const s16x8*)(&Bwin[cur][g << 3]); \
    } \
    __builtin_amdgcn_s_setprio(1); \
    _Pragma("unroll") \
    for (int i = 0; i < 4; ++i) \
        _Pragma("unroll") \
        for (int j = 0; j < 4; ++j) \
            acc[i][j] = __builtin_amdgcn_mfma_f32_16x16x32_bf16(USE[i], bfr[j], acc[i][j], 0, 0, 0); \
    __builtin_amdgcn_s_setprio(0); \
}

__global__ __launch_bounds__(256) void conv9_kernel(
    const u16* __restrict__ WF, const u16* __restrict__ UpadT,
    const float* __restrict__ bout, float* __restrict__ out)
{
    __shared__ __align__(16) u16 Bwin[2][256*32];
    const int id  = blockIdx.x;                 // 0..863
    const int lid = (id & 7) * 108 + (id >> 3); // contiguous chunk per XCD
    const int mt  = lid / 216;
    const int r1  = lid % 216;
    const int b   = r1 / 27;
    const int nt  = r1 % 27;
    const int m0 = mt << 7, n0 = nt << 7;

    const int t = threadIdx.x;
    const int lane = t & 63;
    const int w    = __builtin_amdgcn_readfirstlane(t >> 6);
    const int wm   = (w >> 1) * 64;
    const int wn   = (w & 1) * 64;
    const int l15  = lane & 15;
    const int hi   = lane >> 4;     // 0..3
    const int lrow = lane >> 2;     // staging row within 16-block
    const int lq   = lane & 3;      // staging granule slot
    const int mbase = wm >> 4;

    f32x4 acc[4][4];
    #pragma unroll
    for (int i = 0; i < 4; ++i)
        #pragma unroll
        for (int j = 0; j < 4; ++j) { acc[i][j][0]=0.f; acc[i][j][1]=0.f; acc[i][j][2]=0.f; acc[i][j][3]=0.f; }

    const u16* Ub = UpadT + (ll)b * UROWS * CIN;

    STAGEB(0, 0);
    __syncthreads();

    for (int kc = 0; kc < 16; ++kc) {
        const int cur = kc & 1;
        s16x8 af0[4], af1[4], af2[4];
        // A-frags for taps 0,1 FIRST (oldest in vmcnt queue -> counted waits)
        {
            const u16* a0 = WF + (ll)((mt*9 + 0)*16 + kc) * 4096;
            const u16* a1 = WF + (ll)((mt*9 + 1)*16 + kc) * 4096;
            #pragma unroll
            for (int i = 0; i < 4; ++i)
                af0[i] = *(const s16x8*)(a0 + ((mbase + i)*64 + lane)*8);
            #pragma unroll
            for (int i = 0; i < 4; ++i)
                af1[i] = *(const s16x8*)(a1 + ((mbase + i)*64 + lane)*8);
        }
        __builtin_amdgcn_sched_barrier(0);
        if (kc < 15) STAGEB(cur ^ 1, kc + 1);
        __builtin_amdgcn_sched_barrier(0);
        TAP2(0, af0, af2) TAP2(1, af1, af0) TAP2(2, af2, af1)
        TAP2(3, af0, af2) TAP2(4, af1, af0) TAP2(5, af2, af1)
        TAP2(6, af0, af2) TAP2(7, af1, af0) TAP2(8, af2, af0)
        __syncthreads();
    }

    #pragma unroll
    for (int i = 0; i < 4; ++i) {
        #pragma unroll
        for (int j = 0; j < 4; ++j) {
            const int pc = n0 + wn + j*16 + l15;
            const int y = pc / PADW, xx = pc % PADW;
            if (y >= 1 && y <= 56 && xx >= 1 && xx <= 56) {
                const int p = (y - 1) * 56 + (xx - 1);
                #pragma unroll
                for (int r = 0; r < 4; ++r) {
                    const int m = m0 + wm + i*16 + hi*4 + r;
                    out[((ll)b * CIN + m) * HW + p] = acc[i][j][r] + bout[m];
                }
            }
        }
    }
}

// ---------------------------------------------------------------------------
extern "C" void kernel_launch(void* const* d_in, const int* in_sizes, int n_in,
                              void* d_out, int out_size, void* d_ws, size_t ws_size,
                              hipStream_t stream)
{
    const float* x    = (const float*)d_in[0];
    const float* WA   = (const float*)d_in[1];
    const float* bA   = (const float*)d_in[2];
    const float* WB   = (const float*)d_in[3];
    const float* bB   = (const float*)d_in[4];
    const float* WV   = (const float*)d_in[5];
    const float* bV   = (const float*)d_in[6];
    const float* WAs  = (const float*)d_in[7];
    const float* bAs  = (const float*)d_in[8];
    const float* WBs  = (const float*)d_in[9];
    const float* bBs  = (const float*)d_in[10];
    const float* WVs  = (const float*)d_in[11];
    const float* bVs  = (const float*)d_in[12];
    const float* WE   = (const float*)d_in[13];
    const float* bE   = (const float*)d_in[14];
    const float* bng  = (const float*)d_in[15];
    const float* bnb  = (const float*)d_in[16];
    const float* bnm  = (const float*)d_in[17];
    const float* bnv  = (const float*)d_in[18];
    const float* Wout = (const float*)d_in[19];
    const float* bout = (const float*)d_in[20];
    float* out = (float*)d_out;

    char* ws = (char*)d_ws;
    u16*   xT    = (u16*)  (ws + OFF_XT);
    u16*   P     = (u16*)  (ws + OFF_P);
    u16*   SAT   = (u16*)  (ws + OFF_SAT);
    u16*   GHT   = (u16*)  (ws + OFF_GHT);
    u16*   WGHT  = (u16*)  (ws + OFF_ZT);
    float* partG = (float*)(ws + OFF_ZT);    // consumed by reduce_gh before WGHT written
    float* partH = (float*)(ws + OFF_ZST);
    u16*   Upad  = (u16*)  (ws + OFF_UPAD);
    u16*   Wcat  = (u16*)  (ws + OFF_WCAT);
    float* bcat  = (float*)(ws + OFF_BCAT);
    u16*   WEb   = (u16*)  (ws + OFF_WEB);
    u16*   Ws9f  = (u16*)  (ws + OFF_WS9);
    float* scale = (float*)(ws + OFF_SCALE);
    float* shift = (float*)(ws + OFF_SHIFT);

    // 1. weight packing / bn fold / conv-weight frag permutation
    prep_kernel<<<2048, 256, 0, stream>>>(WA, WB, WV, WAs, WBs, WVs,
                                          bA, bB, bV, bAs, bBs, bVs,
                                          WE, bng, bnb, bnm, bnv, Wout,
                                          Wcat, bcat, WEb, Ws9f, scale, shift);

    // 2. xT[p][c] = bf16(x[c][p])
    transpose_kernel<float><<<dim3(98, 16, 8), 256, 0, stream>>>(
        x, xT, CIN, HW, (ll)CIN * HW, (ll)HW * CIN, CIN, 0);

    // 3. fused projection: P[o][p]
    gemm_bt_kernel<0><<<dim3(25, 5, 8), 256, 0, stream>>>(
        Wcat, CIN, 0, xT, CIN, (ll)HW * CIN, P, HW, (ll)MPROJ * HW,
        MPROJ, HW, CIN, bcat);

    // 4. spatial softmax for B rows
    softmax_rows_kernel<<<dim3(64, 8), 256, 0, stream>>>(P);

    // 5. channel softmax for V / B_S / V_S
    softmax_cols_kernel<<<dim3(98, 3), 256, 0, stream>>>(P);

    // 6. transposes into SAT: cols 0..63 = softV^T, cols 64..191 = A_S^T
    transpose_kernel<u16><<<dim3(98, 2, 8), 256, 0, stream>>>(
        P + (ll)192 * HW, SAT, CN, HW, (ll)MPROJ * HW, (ll)HW * 192, 192, 0);
    transpose_kernel<u16><<<dim3(98, 4, 8), 256, 0, stream>>>(
        P + (ll)256 * HW, SAT, CM, HW, (ll)MPROJ * HW, (ll)HW * 192, 192, 64);

    // 7. G/H split-K partials + reduce into GHT (transposed)
    gemm_gh_kernel<<<112, 256, 0, stream>>>(P, partG, partH);
    reduce_gh_kernel<<<768, 256, 0, stream>>>(partG, partH, GHT);

    // 8. WGHT[cout][0..63]=W1T, [64..191]=W2T : A=WEb[512][128], Bt=GHT[192][128]
    gemm_bt_kernel<1><<<dim3(2, 4, 8), 256, 0, stream>>>(
        WEb, CM, 0, GHT, CM, (ll)192 * CM, WGHT, 192, (ll)512 * 192,
        512, 192, CM, nullptr);

    // 9. zero padded residual buffer (borders + guards)
    hipMemsetAsync(Upad, 0, (size_t)BATCH * UROWS * CIN * sizeof(u16), stream);

    // 10. fused E1+E2+residual into Upad interior
    e12_kernel<<<dim3(4, 25, 8), 256, 0, stream>>>(
        SAT, WGHT, xT, bE, scale, shift, Upad);

    // 11. 3x3 conv: window-staged shift-GEMMs (issue-ordered pipeline)
    conv9_kernel<<<864, 256, 0, stream>>>(Ws9f, Upad, bout, out);

    (void)in_sizes; (void)n_in; (void)out_size; (void)ws_size;
}